// Round 9
// baseline (4498.166 us; speedup 1.0000x reference)
//
#include <hip/hip_runtime.h>
#include <math.h>

// ---------------------------------------------------------------------------
// Reformer forward. Round-8 structure (3326 us) + 2-tile-deep register
// prefetch in gemm_mfma: tile k+2's global loads issue at tile k, covering
// LLC latency across the two s_waitcnt vmcnt(0) barrier drains per tile
// (round-8 counters: SPLIT2 == SPLIT3 duration -> stall-bound, not MFMA).
// GEMMs v/out/ff: in-kernel split-bf16 MFMA (3-way l0, 2-way l1). QK
// projections fp32+fp64-acc (feed LSH argmax). Attention: MFMA (l0 3-plane
// Q/K, l1 2-plane; P/V 2-plane).
// B=4, L=4096, D=512, H=8, DH=64, FF=2048, EL=2, BS=64, NHASH=4
// ---------------------------------------------------------------------------

typedef __attribute__((ext_vector_type(8))) __bf16 bf16x8;
typedef __attribute__((ext_vector_type(4))) float floatx4;

__device__ __forceinline__ unsigned short f2bf(float f) {
  union { float f; unsigned int u; } x; x.f = f;
  unsigned int r = x.u + 0x7fffu + ((x.u >> 16) & 1u);
  return (unsigned short)(r >> 16);
}
__device__ __forceinline__ float bf2f(unsigned short u) {
  union { unsigned int u; float f; } x; x.u = ((unsigned int)u) << 16;
  return x.f;
}
__device__ __forceinline__ float gelu_f(float x) {
  return 0.5f * x * (1.0f + erff(x * 0.70710678118654752440f));
}

// ------------------------- positional-encoding table -----------------------
__global__ __launch_bounds__(256) void pe_kernel(float* __restrict__ pe)
{
  int t = blockIdx.x;
#pragma unroll
  for (int rep = 0; rep < 2; ++rep) {
    int d = threadIdx.x + rep * 256;
    float cf = (float)(-9.210340371976184 / 512.0);
    float xf = (float)(d & ~1) * cf;
    float freq = (float)exp((double)xf);
    float angf = (float)t * freq;
    double a = (double)angf;
    pe[t * 512 + d] = (float)((d & 1) ? cos(a) : sin(a));
  }
}

// ------------------------- embedding ---------------------------------------
__global__ __launch_bounds__(256) void embed_kernel(
    const float* __restrict__ x_enc, const float* __restrict__ x_dec,
    const int* __restrict__ xm_enc, const int* __restrict__ xm_dec,
    const float* __restrict__ conv_w,
    const float* __restrict__ month, const float* __restrict__ day,
    const float* __restrict__ wday, const float* __restrict__ hour,
    const float* __restrict__ minute, const float* __restrict__ pe,
    float* __restrict__ h)
{
  int idx = blockIdx.x;
  int b = idx >> 12, t = idx & 4095;
  __shared__ float xv[21];
  __shared__ int mi[5];
  int tid = threadIdx.x;
  if (tid < 21) {
    int w = tid / 7, c = tid % 7;
    int s = (t + w + 4095) & 4095;
    xv[tid] = (s < 3584) ? x_enc[(s + b*3584)*7 + c]
                         : x_dec[((s - 3584) + b*512)*7 + c];
  }
  if (tid >= 32 && tid < 37) {
    int j = tid - 32;
    mi[j] = (t < 3584) ? xm_enc[(b*3584 + t)*5 + j]
                       : xm_dec[(b*512 + (t - 3584))*5 + j];
  }
  __syncthreads();
  int m0 = mi[0], m1 = mi[1], m2 = mi[2], m3 = mi[3], m4 = mi[4];
#pragma unroll
  for (int rep = 0; rep < 2; ++rep) {
    int d = tid + rep*256;
    float tok = 0.f;
#pragma unroll
    for (int wc = 0; wc < 21; ++wc) tok += xv[wc] * conv_w[wc*512 + d];
    float temp = month[m0*512+d] + day[m1*512+d] + wday[m2*512+d]
               + hour[m3*512+d] + minute[m4*512+d];
    h[(size_t)idx*512 + d] = tok + temp + pe[t*512 + d];
  }
}

// ------------------------- precise fp32 GEMM (QK projections only) ---------
template<int ACT>
__global__ __launch_bounds__(256) void gemm_kernel(
    const float* __restrict__ A, const float* __restrict__ W,
    const float* __restrict__ bias, float* __restrict__ C,
    int M, int N, int K)
{
  __shared__ float As[8][132];
  __shared__ float Bs[8][132];
  int tid = threadIdx.x;
  int bm = blockIdx.x, bn = blockIdx.y;
  int tr = tid >> 4, tc = tid & 15;
  double acc[8][8];
  float tt[8][8];
#pragma unroll
  for (int i=0;i<8;++i)
#pragma unroll
    for (int j=0;j<8;++j) { acc[i][j]=0.0; tt[i][j]=0.f; }

  int am  = tid >> 1;
  int at  = (tid & 1) * 4;
  int bkr = tid >> 5;
  int bn4 = (tid & 31) * 4;
  const float* Aptr = A + (size_t)(bm*128 + am)*K + at;
  const float* Bptr = W + (size_t)bkr*N + bn*128 + bn4;

  int phase = 0;
  for (int k0 = 0; k0 < K; k0 += 8) {
    float4 a4 = *(const float4*)(Aptr + k0);
    float4 b4 = *(const float4*)(Bptr + (size_t)k0*N);
    __syncthreads();
    As[at+0][am] = a4.x; As[at+1][am] = a4.y;
    As[at+2][am] = a4.z; As[at+3][am] = a4.w;
    *(float4*)&Bs[bkr][bn4] = b4;
    __syncthreads();
#pragma unroll
    for (int k=0;k<8;++k) {
      float4 a0 = *(const float4*)&As[k][tr*8];
      float4 a1 = *(const float4*)&As[k][tr*8+4];
      float4 b0 = *(const float4*)&Bs[k][tc*8];
      float4 b1 = *(const float4*)&Bs[k][tc*8+4];
      float av[8] = {a0.x,a0.y,a0.z,a0.w,a1.x,a1.y,a1.z,a1.w};
      float bv[8] = {b0.x,b0.y,b0.z,b0.w,b1.x,b1.y,b1.z,b1.w};
#pragma unroll
      for (int i=0;i<8;++i)
#pragma unroll
        for (int j=0;j<8;++j) tt[i][j] += av[i]*bv[j];
    }
    phase ^= 1;
    if (!phase) {
#pragma unroll
      for (int i=0;i<8;++i)
#pragma unroll
        for (int j=0;j<8;++j) { acc[i][j] += (double)tt[i][j]; tt[i][j]=0.f; }
    }
  }
  int row0 = bm*128 + tr*8;
  int col0 = bn*128 + tc*8;
  float bvb[8];
#pragma unroll
  for (int j=0;j<8;++j) bvb[j] = bias ? bias[col0+j] : 0.f;
#pragma unroll
  for (int i=0;i<8;++i) {
    float o[8];
#pragma unroll
    for (int j=0;j<8;++j) {
      float vv = (float)acc[i][j] + bvb[j];
      if (ACT==1) vv = gelu_f(vv);
      o[j] = vv;
    }
    float4* dst = (float4*)(C + (size_t)(row0+i)*N + col0);
    dst[0] = make_float4(o[0],o[1],o[2],o[3]);
    dst[1] = make_float4(o[4],o[5],o[6],o[7]);
  }
}

// ------------------------- weight transpose + bf16 split prepass -----------
// W: [K][N] fp32 -> Wt planes: [p][N][K] bf16 (k-contiguous for MFMA frags)
template<int SPLIT>
__global__ __launch_bounds__(256) void wsplit_kernel(
    const float* __restrict__ W, unsigned short* __restrict__ Wt, int K, int N)
{
  __shared__ float tile[32][33];
  int k0 = blockIdx.x*32, n0 = blockIdx.y*32;
  int tid = threadIdx.x;
  int kk = tid >> 3, nn4 = (tid & 7)*4;
  float4 w4 = *(const float4*)(W + (size_t)(k0+kk)*N + n0 + nn4);
  tile[kk][nn4+0]=w4.x; tile[kk][nn4+1]=w4.y;
  tile[kk][nn4+2]=w4.z; tile[kk][nn4+3]=w4.w;
  __syncthreads();
  int n = tid >> 3, k4 = (tid & 7)*4;
  unsigned short o[3][4];
#pragma unroll
  for (int j=0;j<4;++j) {
    float v = tile[k4+j][n];
    unsigned short h0 = f2bf(v);
    float r = v - bf2f(h0);
    unsigned short h1 = f2bf(r);
    o[0][j] = h0; o[1][j] = h1;
    if (SPLIT==3) { float r2 = r - bf2f(h1); o[2][j] = f2bf(r2); }
  }
#pragma unroll
  for (int p=0;p<SPLIT;++p) {
    ushort4* d = (ushort4*)(Wt + (size_t)p*N*K + (size_t)(n0+n)*K + k0 + k4);
    *d = make_ushort4(o[p][0], o[p][1], o[p][2], o[p][3]);
  }
}

// ------------------------- split-bf16 MFMA GEMM (in-kernel A split) --------
// C = A(fp32 MxK) @ W(KxN, pre-split Wt planes), 128x128 tile, BK=32,
// 16x16x32 bf16 MFMA, 4 waves each computing a 64x64 quadrant.
// 2-tile-deep register prefetch: tile k+2 loads issue at tile k.
template<int SPLIT, int ACT>
__global__ __launch_bounds__(256, 3) void gemm_mfma(
    const float* __restrict__ A, const unsigned short* __restrict__ Wt,
    const float* __restrict__ bias, float* __restrict__ C,
    int M, int N, int K)
{
  constexpr int RS = SPLIT*32 + 8;
  __shared__ __align__(16) unsigned short smem[2*128*RS];
  unsigned short* sA = smem;
  unsigned short* sB = smem + 128*RS;
  float* sE = (float*)smem;

  int tid = threadIdx.x;
  int bm = blockIdx.x, bn = blockIdx.y;
  int lane = tid & 63, wave = tid >> 6;
  int wm = wave & 1, wn = wave >> 1;
  int fr = lane & 15, fk = (lane >> 4) * 8;

  floatx4 acc[4][4];
#pragma unroll
  for (int i=0;i<4;++i)
#pragma unroll
    for (int j=0;j<4;++j) acc[i][j] = (floatx4){0.f,0.f,0.f,0.f};

  int row = tid >> 1, kseg = (tid & 1) * 16;
  const float* aSrc = A + (size_t)(bm*128 + row)*K + kseg;
  const unsigned short* bSrc = Wt + (size_t)(bn*128 + row)*K + kseg;

  // double register buffers: slot holds tile (k0 + slot*32)
  float4 av4[2][4];
  uint4 bv[2][SPLIT][2];
#pragma unroll
  for (int s=0;s<2;++s) {
    int ko = s*32;
    if (ko < K) {
#pragma unroll
      for (int q=0;q<4;++q) av4[s][q] = *(const float4*)(aSrc + ko + q*4);
#pragma unroll
      for (int p=0;p<SPLIT;++p) {
        const unsigned short* bp = bSrc + (size_t)p*N*K + ko;
        bv[s][p][0] = *(const uint4*)(bp);
        bv[s][p][1] = *(const uint4*)(bp + 8);
      }
    }
  }

  for (int k0 = 0; k0 < K; k0 += 32) {
    int cur = (k0 >> 5) & 1;
    __syncthreads();
    unsigned short us[SPLIT][16];
    const float* ff = (const float*)av4[cur];
#pragma unroll
    for (int i=0;i<16;++i) {
      float v = ff[i];
      unsigned short h0 = f2bf(v);
      float r = v - bf2f(h0);
      us[0][i] = h0;
      unsigned short h1 = f2bf(r);
      us[1][i] = h1;
      if (SPLIT==3) { float r2 = r - bf2f(h1); us[2][i] = f2bf(r2); }
    }
#pragma unroll
    for (int p=0;p<SPLIT;++p) {
      uint4* d = (uint4*)&sA[row*RS + p*32 + kseg];
      d[0] = *(const uint4*)&us[p][0];
      d[1] = *(const uint4*)&us[p][8];
      uint4* db = (uint4*)&sB[row*RS + p*32 + kseg];
      db[0] = bv[cur][p][0];
      db[1] = bv[cur][p][1];
    }
    __syncthreads();
    // prefetch tile k0+64 into the slot just freed (2 tiles ahead)
    if (k0 + 64 < K) {
#pragma unroll
      for (int q=0;q<4;++q) av4[cur][q] = *(const float4*)(aSrc + k0 + 64 + q*4);
#pragma unroll
      for (int p=0;p<SPLIT;++p) {
        const unsigned short* bp = bSrc + (size_t)p*N*K + k0 + 64;
        bv[cur][p][0] = *(const uint4*)(bp);
        bv[cur][p][1] = *(const uint4*)(bp + 8);
      }
    }

    bf16x8 aF[4][SPLIT];
#pragma unroll
    for (int mt=0;mt<4;++mt)
#pragma unroll
      for (int p=0;p<SPLIT;++p)
        aF[mt][p] = *(const bf16x8*)&sA[(wm*64 + mt*16 + fr)*RS + p*32 + fk];
#pragma unroll
    for (int nt=0;nt<4;++nt) {
      bf16x8 bF[SPLIT];
#pragma unroll
      for (int p=0;p<SPLIT;++p)
        bF[p] = *(const bf16x8*)&sB[(wn*64 + nt*16 + fr)*RS + p*32 + fk];
#pragma unroll
      for (int mt=0;mt<4;++mt) {
        floatx4 c = acc[mt][nt];
        if (SPLIT==3) {
          c = __builtin_amdgcn_mfma_f32_16x16x32_bf16(aF[mt][2], bF[0], c, 0,0,0);
          c = __builtin_amdgcn_mfma_f32_16x16x32_bf16(aF[mt][1], bF[1], c, 0,0,0);
          c = __builtin_amdgcn_mfma_f32_16x16x32_bf16(aF[mt][0], bF[2], c, 0,0,0);
        }
        c = __builtin_amdgcn_mfma_f32_16x16x32_bf16(aF[mt][1], bF[0], c, 0,0,0);
        c = __builtin_amdgcn_mfma_f32_16x16x32_bf16(aF[mt][0], bF[1], c, 0,0,0);
        c = __builtin_amdgcn_mfma_f32_16x16x32_bf16(aF[mt][0], bF[0], c, 0,0,0);
        acc[mt][nt] = c;
      }
    }
  }

  // epilogue: C/D layout col = lane&15, row = (lane>>4)*4 + reg  [m89]
  __syncthreads();
#pragma unroll
  for (int half = 0; half < 2; ++half) {
    if (wm == half) {
#pragma unroll
      for (int nt=0;nt<4;++nt) {
        int cl = wn*64 + nt*16 + fr;
        float bb = bias ? bias[bn*128 + cl] : 0.f;
#pragma unroll
        for (int mt=0;mt<4;++mt) {
          int r0 = mt*16 + (lane>>4)*4;
#pragma unroll
          for (int j=0;j<4;++j) {
            float vv = acc[mt][nt][j] + bb;
            if (ACT==1) vv = gelu_f(vv);
            sE[(r0+j)*132 + cl] = vv;
          }
        }
      }
    }
    __syncthreads();
#pragma unroll
    for (int it=0; it<8; ++it) {
      int idx = it*256 + tid;
      int rr = idx >> 5, c4 = (idx & 31) * 4;
      float4 vv = *(const float4*)&sE[rr*132 + c4];
      *(float4*)(C + (size_t)(bm*128 + half*64 + rr)*N + bn*128 + c4) = vv;
    }
    __syncthreads();
  }
}

// ------------------------- LSH hashing (fp64 accumulate) -------------------
__global__ __launch_bounds__(256) void hash_kernel(
    const float* __restrict__ qk, const float* __restrict__ rot,
    unsigned char* __restrict__ buckets)
{
  __shared__ float q[2][64];
  __shared__ double rv[2][128];
  int half = threadIdx.x >> 7;
  int lt = threadIdx.x & 127;
  int g = blockIdx.x*2 + half;
  int bh = g >> 12, t = g & 4095;
  int b = bh >> 3, hd = bh & 7;
  if (lt < 64)
    q[half][lt] = qk[((size_t)(b*4096 + t))*512 + hd*64 + lt];
  __syncthreads();
  double acc = 0.0;
#pragma unroll 8
  for (int f=0; f<64; ++f) acc += (double)q[half][f] * (double)rot[f*128 + lt];
  rv[half][lt] = acc;
  __syncthreads();
  if (lt < 4) {
    const double* r = &rv[half][lt*32];
    double best = r[0]; int bi = 0;
#pragma unroll
    for (int j=1; j<64; ++j) {
      double v = (j < 32) ? r[j] : -r[j-32];
      if (v > best) { best = v; bi = j; }
    }
    buckets[((size_t)(bh*4 + lt))*4096 + t] = (unsigned char)bi;
  }
}

// ------------------------- stable counting sort per (bh, round) ------------
__global__ __launch_bounds__(64) void sort_kernel(
    const unsigned char* __restrict__ buckets, int* __restrict__ st)
{
  __shared__ unsigned char sb[4096];
  __shared__ int cnts[64];
  int tid = threadIdx.x;
  const unsigned int* src4 = (const unsigned int*)(buckets + (size_t)blockIdx.x*4096);
  unsigned int* sb4 = (unsigned int*)sb;
  for (int i=tid; i<1024; i+=64) sb4[i] = src4[i];
  __syncthreads();
  unsigned int me = (unsigned int)tid;
  int cnt = 0;
  for (int t4=0; t4<1024; ++t4) {
    unsigned int w = sb4[t4];
    cnt += ((w & 255u) == me) + (((w>>8)&255u) == me)
         + (((w>>16)&255u) == me) + ((w>>24) == me);
  }
  cnts[tid] = cnt;
  __syncthreads();
  int base = 0;
  for (int j=0;j<tid;++j) base += cnts[j];
  int* dst = st + (size_t)blockIdx.x*4096;
  for (int t4=0; t4<1024; ++t4) {
    unsigned int w = sb4[t4];
#pragma unroll
    for (int q=0;q<4;++q)
      if (((w >> (8*q)) & 255u) == me) dst[base++] = t4*4 + q;
  }
}

// ------------------------- chunked attention, MFMA -------------------------
template<int SQ>
__global__ __launch_bounds__(256) void attn_mfma(
    const float* __restrict__ qk, const float* __restrict__ v,
    const int* __restrict__ st, float* __restrict__ osc,
    float* __restrict__ logits)
{
  constexpr int RQ = 72;
  constexpr int RP = 136;
  constexpr int QKE = SQ*128*RQ;
  constexpr int PVE = 2*64*RP*2;
  constexpr int UE = (QKE > PVE ? QKE : PVE);
  __shared__ __align__(16) unsigned short uni[UE];
  __shared__ int sPos[128];
  __shared__ float sInv[128];
  unsigned short* sQK = uni;
  unsigned short* sP  = uni;
  unsigned short* sVT = uni + 2*64*RP;

  int tid = threadIdx.x;
  int bh = blockIdx.x >> 8;
  int c  = blockIdx.x & 255;
  int b = bh >> 3, hd = bh & 7;
  int r = c >> 6;
  int lane = tid & 63, wave = tid >> 6;
  int fr = lane & 15, fq = lane >> 4;
  int fk = fq * 8;

  if (tid < 128) {
    int cprev = (c + 255) & 255;
    int slot = (tid < 64) ? (c*64 + tid) : (cprev*64 + tid - 64);
    sPos[tid] = st[bh*16384 + slot];
  }
  __syncthreads();

  int row = tid >> 1, ks2 = (tid & 1) * 32;
  float vreg[32];
  {
    size_t rbase = ((size_t)(b*4096 + sPos[row]))*512 + hd*64 + ks2;
    const float* src  = qk + rbase;
    const float* vsrc = v  + rbase;
    float qreg[32];
    float ss = 0.f;
#pragma unroll
    for (int i=0;i<32;i+=4) {
      float4 x = *(const float4*)(src + i);
      qreg[i]=x.x; qreg[i+1]=x.y; qreg[i+2]=x.z; qreg[i+3]=x.w;
      ss += x.x*x.x + x.y*x.y + x.z*x.z + x.w*x.w;
      float4 y = *(const float4*)(vsrc + i);
      vreg[i]=y.x; vreg[i+1]=y.y; vreg[i+2]=y.z; vreg[i+3]=y.w;
    }
    ss += __shfl_xor(ss, 1, 64);
    if ((tid & 1) == 0) sInv[row] = 1.0f / fmaxf(sqrtf(ss), 1e-12f);
    unsigned short us[3][32];
#pragma unroll
    for (int i=0;i<32;++i) {
      float vv = qreg[i];
      unsigned short h0 = f2bf(vv);
      float r1 = vv - bf2f(h0);
      unsigned short h1 = f2bf(r1);
      us[0][i] = h0; us[1][i] = h1;
      if (SQ==3) { float r2 = r1 - bf2f(h1); us[2][i] = f2bf(r2); }
    }
#pragma unroll
    for (int p=0;p<SQ;++p) {
      uint4* d = (uint4*)&sQK[p*128*RQ + row*RQ + ks2];
      d[0] = *(const uint4*)&us[p][0];
      d[1] = *(const uint4*)&us[p][8];
      d[2] = *(const uint4*)&us[p][16];
      d[3] = *(const uint4*)&us[p][24];
    }
  }
  __syncthreads();

  floatx4 s[8];
#pragma unroll
  for (int nt=0;nt<8;++nt) s[nt] = (floatx4){0.f,0.f,0.f,0.f};
#pragma unroll
  for (int ks=0; ks<2; ++ks) {
    bf16x8 aQ[SQ];
#pragma unroll
    for (int p=0;p<SQ;++p)
      aQ[p] = *(const bf16x8*)&sQK[p*128*RQ + (wave*16 + fr)*RQ + ks*32 + fk];
#pragma unroll
    for (int nt=0;nt<8;++nt) {
      bf16x8 bK[SQ];
#pragma unroll
      for (int p=0;p<SQ;++p)
        bK[p] = *(const bf16x8*)&sQK[p*128*RQ + (nt*16 + fr)*RQ + ks*32 + fk];
      floatx4 cc = s[nt];
      if (SQ==3) {
        cc = __builtin_amdgcn_mfma_f32_16x16x32_bf16(aQ[2], bK[0], cc, 0,0,0);
        cc = __builtin_amdgcn_mfma_f32_16x16x32_bf16(aQ[1], bK[1], cc, 0,0,0);
        cc = __builtin_amdgcn_mfma_f32_16x16x32_bf16(aQ[0], bK[2], cc, 0,0,0);
      }
      cc = __builtin_amdgcn_mfma_f32_16x16x32_bf16(aQ[1], bK[0], cc, 0,0,0);
      cc = __builtin_amdgcn_mfma_f32_16x16x32_bf16(aQ[0], bK[1], cc, 0,0,0);
      cc = __builtin_amdgcn_mfma_f32_16x16x32_bf16(aQ[0], bK[0], cc, 0,0,0);
      s[nt] = cc;
    }
  }

  int ipos[4];
#pragma unroll
  for (int reg=0;reg<4;++reg) ipos[reg] = sPos[wave*16 + fq*4 + reg];
  float dv[8][4];
  float mx[4] = {-1e30f,-1e30f,-1e30f,-1e30f};
#pragma unroll
  for (int nt=0;nt<8;++nt) {
    float invj = sInv[nt*16 + fr];
    int jpos = sPos[nt*16 + fr];
#pragma unroll
    for (int reg=0;reg<4;++reg) {
      float d = s[nt][reg] * invj * 0.125f;
      if (jpos == ipos[reg]) d = -5.0e4f;
      dv[nt][reg] = d;
      mx[reg] = fmaxf(mx[reg], d);
    }
  }
#pragma unroll
  for (int reg=0;reg<4;++reg) {
    mx[reg] = fmaxf(mx[reg], __shfl_xor(mx[reg], 1, 64));
    mx[reg] = fmaxf(mx[reg], __shfl_xor(mx[reg], 2, 64));
    mx[reg] = fmaxf(mx[reg], __shfl_xor(mx[reg], 4, 64));
    mx[reg] = fmaxf(mx[reg], __shfl_xor(mx[reg], 8, 64));
  }
  float sum[4] = {0.f,0.f,0.f,0.f};
#pragma unroll
  for (int nt=0;nt<8;++nt)
#pragma unroll
    for (int reg=0;reg<4;++reg) sum[reg] += expf(dv[nt][reg] - mx[reg]);
  float lse[4];
#pragma unroll
  for (int reg=0;reg<4;++reg) {
    sum[reg] += __shfl_xor(sum[reg], 1, 64);
    sum[reg] += __shfl_xor(sum[reg], 2, 64);
    sum[reg] += __shfl_xor(sum[reg], 4, 64);
    sum[reg] += __shfl_xor(sum[reg], 8, 64);
    lse[reg] = mx[reg] + logf(sum[reg]);
  }
  if (fr == 0) {
#pragma unroll
    for (int reg=0;reg<4;++reg)
      logits[((size_t)(bh*4 + r))*4096 + ipos[reg]] = lse[reg];
  }
#pragma unroll
  for (int nt=0;nt<8;++nt)
#pragma unroll
    for (int reg=0;reg<4;++reg) dv[nt][reg] = expf(dv[nt][reg] - lse[reg]);

  __syncthreads();

#pragma unroll
  for (int nt=0;nt<8;++nt) {
    int key = nt*16 + fr;
#pragma unroll
    for (int reg=0;reg<4;++reg) {
      int m = wave*16 + fq*4 + reg;
      float p = dv[nt][reg];
      unsigned short h0 = f2bf(p);
      sP[0*64*RP + m*RP + key] = h0;
      sP[1*64*RP + m*RP + key] = f2bf(p - bf2f(h0));
    }
  }
#pragma unroll
  for (int i=0;i<32;++i) {
    int dh = ks2 + i;
    float vv = vreg[i];
    unsigned short h0 = f2bf(vv);
    sVT[0*64*RP + dh*RP + row] = h0;
    sVT[1*64*RP + dh*RP + row] = f2bf(vv - bf2f(h0));
  }
  __syncthreads();

  size_t obase = ((size_t)(bh*4 + r)) * 4096;
#pragma unroll
  for (int dt=0;dt<4;++dt) {
    floatx4 o = (floatx4){0.f,0.f,0.f,0.f};
#pragma unroll
    for (int ks=0; ks<4; ++ks) {
      bf16x8 aP0 = *(const bf16x8*)&sP[0*64*RP + (wave*16 + fr)*RP + ks*32 + fk];
      bf16x8 aP1 = *(const bf16x8*)&sP[1*64*RP + (wave*16 + fr)*RP + ks*32 + fk];
      bf16x8 bV0 = *(const bf16x8*)&sVT[0*64*RP + (dt*16 + fr)*RP + ks*32 + fk];
      bf16x8 bV1 = *(const bf16x8*)&sVT[1*64*RP + (dt*16 + fr)*RP + ks*32 + fk];
      o = __builtin_amdgcn_mfma_f32_16x16x32_bf16(aP1, bV1, o, 0,0,0);
      o = __builtin_amdgcn_mfma_f32_16x16x32_bf16(aP1, bV0, o, 0,0,0);
      o = __builtin_amdgcn_mfma_f32_16x16x32_bf16(aP0, bV1, o, 0,0,0);
      o = __builtin_amdgcn_mfma_f32_16x16x32_bf16(aP0, bV0, o, 0,0,0);
    }
    int dh = dt*16 + fr;
#pragma unroll
    for (int reg=0;reg<4;++reg) {
      int m = wave*16 + fq*4 + reg;
      osc[(obase + sPos[m])*64 + dh] = o[reg];
    }
  }
}

// ------------------------- combine rounds + merge heads --------------------
__global__ __launch_bounds__(256) void combine_kernel(
    const float* __restrict__ osc, const float* __restrict__ logits,
    float* __restrict__ merged)
{
  int idx = blockIdx.x;
  int b = idx >> 12, t = idx & 4095;
  int tid = threadIdx.x;
  __shared__ float w[8][4];
  if (tid < 8) {
    size_t lbase = ((size_t)(b*8 + tid)) * 4 * 4096 + t;
    float l0 = logits[lbase], l1 = logits[lbase + 4096],
          l2 = logits[lbase + 8192], l3 = logits[lbase + 12288];
    float m = fmaxf(fmaxf(l0,l1), fmaxf(l2,l3));
    float e0 = expf(l0-m), e1 = expf(l1-m), e2 = expf(l2-m), e3 = expf(l3-m);
    float inv = 1.0f/(e0+e1+e2+e3);
    w[tid][0]=e0*inv; w[tid][1]=e1*inv; w[tid][2]=e2*inv; w[tid][3]=e3*inv;
  }
  __syncthreads();
#pragma unroll
  for (int rep=0; rep<2; ++rep) {
    int d = tid + rep*256;
    int hd = d >> 6, dh = d & 63;
    size_t obase = (((size_t)(b*8 + hd)) * 4 * 4096 + t) * 64 + dh;
    float o = w[hd][0]*osc[obase]
            + w[hd][1]*osc[obase + 262144]
            + w[hd][2]*osc[obase + 524288]
            + w[hd][3]*osc[obase + 786432];
    merged[(size_t)idx*512 + d] = o;
  }
}

// ------------------------- residual + LayerNorm (in-place on h) ------------
__global__ __launch_bounds__(256) void ln_residual_kernel(
    float* __restrict__ h, const float* __restrict__ a,
    const float* __restrict__ g, const float* __restrict__ bb)
{
  int row = blockIdx.x;
  int tid = threadIdx.x;
  size_t base = (size_t)row * 512;
  float x0 = h[base + tid]       + a[base + tid];
  float x1 = h[base + tid + 256] + a[base + tid + 256];
  float s  = x0 + x1;
  float sq = x0*x0 + x1*x1;
#pragma unroll
  for (int off = 32; off > 0; off >>= 1) {
    s  += __shfl_down(s, off, 64);
    sq += __shfl_down(sq, off, 64);
  }
  __shared__ float rs[4], rq[4], sm[2];
  int wv = tid >> 6;
  if ((tid & 63) == 0) { rs[wv] = s; rq[wv] = sq; }
  __syncthreads();
  if (tid == 0) {
    float S = rs[0]+rs[1]+rs[2]+rs[3];
    float Q = rq[0]+rq[1]+rq[2]+rq[3];
    float m = S * (1.0f/512.0f);
    float var = Q * (1.0f/512.0f) - m*m;
    sm[0] = m; sm[1] = rsqrtf(var + 1e-5f);
  }
  __syncthreads();
  float m = sm[0], rstd = sm[1];
  h[base + tid]       = (x0 - m) * rstd * g[tid]       + bb[tid];
  h[base + tid + 256] = (x1 - m) * rstd * g[tid + 256] + bb[tid + 256];
}

// ------------------------- final LN + projection ---------------------------
__global__ __launch_bounds__(256) void final_kernel(
    const float* __restrict__ h, const float* __restrict__ g, const float* __restrict__ bb,
    const float* __restrict__ Wp, const float* __restrict__ bp, float* __restrict__ out)
{
  int idx = blockIdx.x;
  int b = idx >> 9, tp = idx & 511;
  size_t base = ((size_t)(b*4096 + 3584 + tp)) * 512;
  int tid = threadIdx.x;
  float x0 = h[base + tid], x1 = h[base + tid + 256];
  float s = x0 + x1, sq = x0*x0 + x1*x1;
#pragma unroll
  for (int off = 32; off > 0; off >>= 1) {
    s  += __shfl_down(s, off, 64);
    sq += __shfl_down(sq, off, 64);
  }
  __shared__ float rs[4], rq[4], sm[2];
  int wv = tid >> 6;
  if ((tid & 63) == 0) { rs[wv] = s; rq[wv] = sq; }
  __syncthreads();
  if (tid == 0) {
    float S = rs[0]+rs[1]+rs[2]+rs[3];
    float Q = rq[0]+rq[1]+rq[2]+rq[3];
    float m = S*(1.f/512.f);
    float var = Q*(1.f/512.f) - m*m;
    sm[0]=m; sm[1]=rsqrtf(var+1e-5f);
  }
  __syncthreads();
  __shared__ float xn[512];
  float m = sm[0], rstd = sm[1];
  xn[tid]     = (x0-m)*rstd*g[tid]     + bb[tid];
  xn[tid+256] = (x1-m)*rstd*g[tid+256] + bb[tid+256];
  __syncthreads();
  if (tid < 224) {
    int col = tid >> 5, lane = tid & 31;
    float p = 0.f;
    for (int f = lane; f < 512; f += 32) p += xn[f]*Wp[f*7 + col];
#pragma unroll
    for (int off=16; off>0; off>>=1) p += __shfl_down(p, off, 32);
    if (lane == 0) out[(size_t)idx*7 + col] = p + bp[col];
  }
}

// ---------------------------------------------------------------------------
extern "C" void kernel_launch(void* const* d_in, const int* in_sizes, int n_in,
                              void* d_out, int out_size, void* d_ws, size_t ws_size,
                              hipStream_t stream)
{
  (void)in_sizes; (void)n_in; (void)out_size; (void)ws_size;
  const float* x_enc  = (const float*)d_in[0];
  const float* x_dec  = (const float*)d_in[1];
  const int*   xm_enc = (const int*)d_in[2];
  const int*   xm_dec = (const int*)d_in[3];
  const float* conv_w = (const float*)d_in[4];
  const float* month  = (const float*)d_in[5];
  const float* day    = (const float*)d_in[6];
  const float* wday   = (const float*)d_in[7];
  const float* hourE  = (const float*)d_in[8];
  const float* minE   = (const float*)d_in[9];
  const float* W_qk   = (const float*)d_in[10];
  const float* W_v    = (const float*)d_in[11];
  const float* W_out  = (const float*)d_in[12];
  const float* b_out  = (const float*)d_in[13];
  const float* rots   = (const float*)d_in[14];
  const float* ln1_g  = (const float*)d_in[15];
  const float* ln1_b  = (const float*)d_in[16];
  const float* W_ff1  = (const float*)d_in[17];
  const float* b_ff1  = (const float*)d_in[18];
  const float* W_ff2  = (const float*)d_in[19];
  const float* b_ff2  = (const float*)d_in[20];
  const float* ln2_g  = (const float*)d_in[21];
  const float* ln2_b  = (const float*)d_in[22];
  const float* lnf_g  = (const float*)d_in[23];
  const float* lnf_b  = (const float*)d_in[24];
  const float* W_proj = (const float*)d_in[25];
  const float* b_proj = (const float*)d_in[26];

  float* h    = (float*)d_ws;            // 8M floats
  float* bufA = h    + 8388608ull;       // 8M
  float* bufB = bufA + 8388608ull;       // 8M
  float* osc  = bufB + 8388608ull;       // 32M (attn out / FFN mid / pe / Wt)
  float* lg   = osc  + 33554432ull;      // 512K
  int*   stp  = (int*)(lg + 524288ull);  // 512K ints
  unsigned char* bkt = (unsigned char*)(stp + 524288ull); // 512KB
  float* pe   = osc;                     // only live during embed
  unsigned short* WtA = (unsigned short*)osc;   // Wt for v/out (osc dead then)
  unsigned short* WtB = (unsigned short*)bufB;  // Wt for ff1/ff2 (bufB dead then)

  pe_kernel<<<4096, 256, 0, stream>>>(pe);
  embed_kernel<<<16384, 256, 0, stream>>>(x_enc, x_dec, xm_enc, xm_dec, conv_w,
                                          month, day, wday, hourE, minE, pe, h);
  for (int l = 0; l < 2; ++l) {
    const float* Wqk = W_qk + (size_t)l*262144;
    const float* Wv  = W_v  + (size_t)l*262144;
    const float* Wo  = W_out+ (size_t)l*262144;
    const float* Wf1 = W_ff1 + (size_t)l*1048576;
    const float* Wf2 = W_ff2 + (size_t)l*1048576;
    const float* rot = rots + (size_t)l*8192;

    // qk projection: precise (feeds LSH argmax directly)
    gemm_kernel<0><<<dim3(128,4), 256, 0, stream>>>(h, Wqk, nullptr, bufA, 16384, 512, 512);
    // v projection: split-bf16 MFMA (x3 on layer 0, x2 on layer 1)
    if (l == 0) {
      wsplit_kernel<3><<<dim3(16,16), 256, 0, stream>>>(Wv, WtA, 512, 512);
      gemm_mfma<3,0><<<dim3(128,4), 256, 0, stream>>>(h, WtA, nullptr, bufB, 16384, 512, 512);
    } else {
      wsplit_kernel<2><<<dim3(16,16), 256, 0, stream>>>(Wv, WtA, 512, 512);
      gemm_mfma<2,0><<<dim3(128,4), 256, 0, stream>>>(h, WtA, nullptr, bufB, 16384, 512, 512);
    }
    hash_kernel<<<65536, 256, 0, stream>>>(bufA, rot, bkt);
    sort_kernel<<<128, 64, 0, stream>>>(bkt, stp);
    if (l == 0)
      attn_mfma<3><<<8192, 256, 0, stream>>>(bufA, bufB, stp, osc, lg);
    else
      attn_mfma<2><<<8192, 256, 0, stream>>>(bufA, bufB, stp, osc, lg);
    combine_kernel<<<16384, 256, 0, stream>>>(osc, lg, bufA);
    // out projection
    if (l == 0) {
      wsplit_kernel<3><<<dim3(16,16), 256, 0, stream>>>(Wo, WtA, 512, 512);
      gemm_mfma<3,0><<<dim3(128,4), 256, 0, stream>>>(bufA, WtA, b_out + l*512, bufB, 16384, 512, 512);
    } else {
      wsplit_kernel<2><<<dim3(16,16), 256, 0, stream>>>(Wo, WtA, 512, 512);
      gemm_mfma<2,0><<<dim3(128,4), 256, 0, stream>>>(bufA, WtA, b_out + l*512, bufB, 16384, 512, 512);
    }
    ln_residual_kernel<<<16384, 256, 0, stream>>>(h, bufB, ln1_g + l*512, ln1_b + l*512);
    // FFN
    if (l == 0) {
      wsplit_kernel<3><<<dim3(16,64), 256, 0, stream>>>(Wf1, WtB, 512, 2048);
      gemm_mfma<3,1><<<dim3(128,16), 256, 0, stream>>>(h, WtB, b_ff1 + l*2048, osc, 16384, 2048, 512);
      wsplit_kernel<3><<<dim3(64,16), 256, 0, stream>>>(Wf2, WtB, 2048, 512);
      gemm_mfma<3,0><<<dim3(128,4), 256, 0, stream>>>(osc, WtB, b_ff2 + l*512, bufA, 16384, 512, 2048);
    } else {
      wsplit_kernel<2><<<dim3(16,64), 256, 0, stream>>>(Wf1, WtB, 512, 2048);
      gemm_mfma<2,1><<<dim3(128,16), 256, 0, stream>>>(h, WtB, b_ff1 + l*2048, osc, 16384, 2048, 512);
      wsplit_kernel<2><<<dim3(64,16), 256, 0, stream>>>(Wf2, WtB, 2048, 512);
      gemm_mfma<2,0><<<dim3(128,4), 256, 0, stream>>>(osc, WtB, b_ff2 + l*512, bufA, 16384, 512, 2048);
    }
    ln_residual_kernel<<<16384, 256, 0, stream>>>(h, bufA, ln2_g + l*512, ln2_b + l*512);
  }
  final_kernel<<<2048, 256, 0, stream>>>(h, lnf_g, lnf_b, W_proj, b_proj, (float*)d_out);
}

// Round 10
// 3642.661 us; speedup vs baseline: 1.2349x; 1.2349x over previous
//
#include <hip/hip_runtime.h>
#include <math.h>

// ---------------------------------------------------------------------------
// Reformer forward. Round-8 structure (3326 us) + 256x128 M-tile gemm_mfma256
// for the FF GEMMs only: halves W-plane staging traffic (the round-8 FF GEMM
// is bound by the ~3.8 TB/s L2-fill wall: 1.34 GB staged over 353 us).
// v/out GEMMs keep the 128x128 round-8 kernel (grid too small for 256-tile).
// GEMMs v/out/ff: in-kernel split-bf16 MFMA (3-way l0 -> feeds l1 LSH hash;
// 2-way l1). QK projections fp32+fp64-acc. Attention: MFMA (round-8).
// B=4, L=4096, D=512, H=8, DH=64, FF=2048, EL=2, BS=64, NHASH=4
// ---------------------------------------------------------------------------

typedef __attribute__((ext_vector_type(8))) __bf16 bf16x8;
typedef __attribute__((ext_vector_type(4))) float floatx4;

__device__ __forceinline__ unsigned short f2bf(float f) {
  union { float f; unsigned int u; } x; x.f = f;
  unsigned int r = x.u + 0x7fffu + ((x.u >> 16) & 1u);
  return (unsigned short)(r >> 16);
}
__device__ __forceinline__ float bf2f(unsigned short u) {
  union { unsigned int u; float f; } x; x.u = ((unsigned int)u) << 16;
  return x.f;
}
__device__ __forceinline__ float gelu_f(float x) {
  return 0.5f * x * (1.0f + erff(x * 0.70710678118654752440f));
}

// ------------------------- positional-encoding table -----------------------
__global__ __launch_bounds__(256) void pe_kernel(float* __restrict__ pe)
{
  int t = blockIdx.x;
#pragma unroll
  for (int rep = 0; rep < 2; ++rep) {
    int d = threadIdx.x + rep * 256;
    float cf = (float)(-9.210340371976184 / 512.0);
    float xf = (float)(d & ~1) * cf;
    float freq = (float)exp((double)xf);
    float angf = (float)t * freq;
    double a = (double)angf;
    pe[t * 512 + d] = (float)((d & 1) ? cos(a) : sin(a));
  }
}

// ------------------------- embedding ---------------------------------------
__global__ __launch_bounds__(256) void embed_kernel(
    const float* __restrict__ x_enc, const float* __restrict__ x_dec,
    const int* __restrict__ xm_enc, const int* __restrict__ xm_dec,
    const float* __restrict__ conv_w,
    const float* __restrict__ month, const float* __restrict__ day,
    const float* __restrict__ wday, const float* __restrict__ hour,
    const float* __restrict__ minute, const float* __restrict__ pe,
    float* __restrict__ h)
{
  int idx = blockIdx.x;
  int b = idx >> 12, t = idx & 4095;
  __shared__ float xv[21];
  __shared__ int mi[5];
  int tid = threadIdx.x;
  if (tid < 21) {
    int w = tid / 7, c = tid % 7;
    int s = (t + w + 4095) & 4095;
    xv[tid] = (s < 3584) ? x_enc[(s + b*3584)*7 + c]
                         : x_dec[((s - 3584) + b*512)*7 + c];
  }
  if (tid >= 32 && tid < 37) {
    int j = tid - 32;
    mi[j] = (t < 3584) ? xm_enc[(b*3584 + t)*5 + j]
                       : xm_dec[(b*512 + (t - 3584))*5 + j];
  }
  __syncthreads();
  int m0 = mi[0], m1 = mi[1], m2 = mi[2], m3 = mi[3], m4 = mi[4];
#pragma unroll
  for (int rep = 0; rep < 2; ++rep) {
    int d = tid + rep*256;
    float tok = 0.f;
#pragma unroll
    for (int wc = 0; wc < 21; ++wc) tok += xv[wc] * conv_w[wc*512 + d];
    float temp = month[m0*512+d] + day[m1*512+d] + wday[m2*512+d]
               + hour[m3*512+d] + minute[m4*512+d];
    h[(size_t)idx*512 + d] = tok + temp + pe[t*512 + d];
  }
}

// ------------------------- precise fp32 GEMM (QK projections only) ---------
template<int ACT>
__global__ __launch_bounds__(256) void gemm_kernel(
    const float* __restrict__ A, const float* __restrict__ W,
    const float* __restrict__ bias, float* __restrict__ C,
    int M, int N, int K)
{
  __shared__ float As[8][132];
  __shared__ float Bs[8][132];
  int tid = threadIdx.x;
  int bm = blockIdx.x, bn = blockIdx.y;
  int tr = tid >> 4, tc = tid & 15;
  double acc[8][8];
  float tt[8][8];
#pragma unroll
  for (int i=0;i<8;++i)
#pragma unroll
    for (int j=0;j<8;++j) { acc[i][j]=0.0; tt[i][j]=0.f; }

  int am  = tid >> 1;
  int at  = (tid & 1) * 4;
  int bkr = tid >> 5;
  int bn4 = (tid & 31) * 4;
  const float* Aptr = A + (size_t)(bm*128 + am)*K + at;
  const float* Bptr = W + (size_t)bkr*N + bn*128 + bn4;

  int phase = 0;
  for (int k0 = 0; k0 < K; k0 += 8) {
    float4 a4 = *(const float4*)(Aptr + k0);
    float4 b4 = *(const float4*)(Bptr + (size_t)k0*N);
    __syncthreads();
    As[at+0][am] = a4.x; As[at+1][am] = a4.y;
    As[at+2][am] = a4.z; As[at+3][am] = a4.w;
    *(float4*)&Bs[bkr][bn4] = b4;
    __syncthreads();
#pragma unroll
    for (int k=0;k<8;++k) {
      float4 a0 = *(const float4*)&As[k][tr*8];
      float4 a1 = *(const float4*)&As[k][tr*8+4];
      float4 b0 = *(const float4*)&Bs[k][tc*8];
      float4 b1 = *(const float4*)&Bs[k][tc*8+4];
      float av[8] = {a0.x,a0.y,a0.z,a0.w,a1.x,a1.y,a1.z,a1.w};
      float bv[8] = {b0.x,b0.y,b0.z,b0.w,b1.x,b1.y,b1.z,b1.w};
#pragma unroll
      for (int i=0;i<8;++i)
#pragma unroll
        for (int j=0;j<8;++j) tt[i][j] += av[i]*bv[j];
    }
    phase ^= 1;
    if (!phase) {
#pragma unroll
      for (int i=0;i<8;++i)
#pragma unroll
        for (int j=0;j<8;++j) { acc[i][j] += (double)tt[i][j]; tt[i][j]=0.f; }
    }
  }
  int row0 = bm*128 + tr*8;
  int col0 = bn*128 + tc*8;
  float bvb[8];
#pragma unroll
  for (int j=0;j<8;++j) bvb[j] = bias ? bias[col0+j] : 0.f;
#pragma unroll
  for (int i=0;i<8;++i) {
    float o[8];
#pragma unroll
    for (int j=0;j<8;++j) {
      float vv = (float)acc[i][j] + bvb[j];
      if (ACT==1) vv = gelu_f(vv);
      o[j] = vv;
    }
    float4* dst = (float4*)(C + (size_t)(row0+i)*N + col0);
    dst[0] = make_float4(o[0],o[1],o[2],o[3]);
    dst[1] = make_float4(o[4],o[5],o[6],o[7]);
  }
}

// ------------------------- weight transpose + bf16 split prepass -----------
// W: [K][N] fp32 -> Wt planes: [p][N][K] bf16 (k-contiguous for MFMA frags)
template<int SPLIT>
__global__ __launch_bounds__(256) void wsplit_kernel(
    const float* __restrict__ W, unsigned short* __restrict__ Wt, int K, int N)
{
  __shared__ float tile[32][33];
  int k0 = blockIdx.x*32, n0 = blockIdx.y*32;
  int tid = threadIdx.x;
  int kk = tid >> 3, nn4 = (tid & 7)*4;
  float4 w4 = *(const float4*)(W + (size_t)(k0+kk)*N + n0 + nn4);
  tile[kk][nn4+0]=w4.x; tile[kk][nn4+1]=w4.y;
  tile[kk][nn4+2]=w4.z; tile[kk][nn4+3]=w4.w;
  __syncthreads();
  int n = tid >> 3, k4 = (tid & 7)*4;
  unsigned short o[3][4];
#pragma unroll
  for (int j=0;j<4;++j) {
    float v = tile[k4+j][n];
    unsigned short h0 = f2bf(v);
    float r = v - bf2f(h0);
    unsigned short h1 = f2bf(r);
    o[0][j] = h0; o[1][j] = h1;
    if (SPLIT==3) { float r2 = r - bf2f(h1); o[2][j] = f2bf(r2); }
  }
#pragma unroll
  for (int p=0;p<SPLIT;++p) {
    ushort4* d = (ushort4*)(Wt + (size_t)p*N*K + (size_t)(n0+n)*K + k0 + k4);
    *d = make_ushort4(o[p][0], o[p][1], o[p][2], o[p][3]);
  }
}

// ------------------------- split-bf16 MFMA GEMM, 128x128 (v/out) -----------
template<int SPLIT, int ACT>
__global__ __launch_bounds__(256, 3) void gemm_mfma(
    const float* __restrict__ A, const unsigned short* __restrict__ Wt,
    const float* __restrict__ bias, float* __restrict__ C,
    int M, int N, int K)
{
  constexpr int RS = SPLIT*32 + 8;
  __shared__ __align__(16) unsigned short smem[2*128*RS];
  unsigned short* sA = smem;
  unsigned short* sB = smem + 128*RS;
  float* sE = (float*)smem;

  int tid = threadIdx.x;
  int bm = blockIdx.x, bn = blockIdx.y;
  int lane = tid & 63, wave = tid >> 6;
  int wm = wave & 1, wn = wave >> 1;
  int fr = lane & 15, fk = (lane >> 4) * 8;

  floatx4 acc[4][4];
#pragma unroll
  for (int i=0;i<4;++i)
#pragma unroll
    for (int j=0;j<4;++j) acc[i][j] = (floatx4){0.f,0.f,0.f,0.f};

  int row = tid >> 1, kseg = (tid & 1) * 16;
  const float* aSrc = A + (size_t)(bm*128 + row)*K + kseg;
  const unsigned short* bSrc = Wt + (size_t)(bn*128 + row)*K + kseg;

  float4 av4[4];
  uint4 bv[SPLIT][2];
#pragma unroll
  for (int q=0;q<4;++q) av4[q] = *(const float4*)(aSrc + q*4);
#pragma unroll
  for (int p=0;p<SPLIT;++p) {
    const unsigned short* bp = bSrc + (size_t)p*N*K;
    bv[p][0] = *(const uint4*)(bp);
    bv[p][1] = *(const uint4*)(bp + 8);
  }

  for (int k0 = 0; k0 < K; k0 += 32) {
    __syncthreads();
    unsigned short us[SPLIT][16];
    const float* ff = (const float*)av4;
#pragma unroll
    for (int i=0;i<16;++i) {
      float v = ff[i];
      unsigned short h0 = f2bf(v);
      float r = v - bf2f(h0);
      us[0][i] = h0;
      unsigned short h1 = f2bf(r);
      us[1][i] = h1;
      if (SPLIT==3) { float r2 = r - bf2f(h1); us[2][i] = f2bf(r2); }
    }
#pragma unroll
    for (int p=0;p<SPLIT;++p) {
      uint4* d = (uint4*)&sA[row*RS + p*32 + kseg];
      d[0] = *(const uint4*)&us[p][0];
      d[1] = *(const uint4*)&us[p][8];
      uint4* db = (uint4*)&sB[row*RS + p*32 + kseg];
      db[0] = bv[p][0];
      db[1] = bv[p][1];
    }
    __syncthreads();
    if (k0 + 32 < K) {
#pragma unroll
      for (int q=0;q<4;++q) av4[q] = *(const float4*)(aSrc + k0 + 32 + q*4);
#pragma unroll
      for (int p=0;p<SPLIT;++p) {
        const unsigned short* bp = bSrc + (size_t)p*N*K + k0 + 32;
        bv[p][0] = *(const uint4*)(bp);
        bv[p][1] = *(const uint4*)(bp + 8);
      }
    }

    bf16x8 aF[4][SPLIT];
#pragma unroll
    for (int mt=0;mt<4;++mt)
#pragma unroll
      for (int p=0;p<SPLIT;++p)
        aF[mt][p] = *(const bf16x8*)&sA[(wm*64 + mt*16 + fr)*RS + p*32 + fk];
#pragma unroll
    for (int nt=0;nt<4;++nt) {
      bf16x8 bF[SPLIT];
#pragma unroll
      for (int p=0;p<SPLIT;++p)
        bF[p] = *(const bf16x8*)&sB[(wn*64 + nt*16 + fr)*RS + p*32 + fk];
#pragma unroll
      for (int mt=0;mt<4;++mt) {
        floatx4 c = acc[mt][nt];
        if (SPLIT==3) {
          c = __builtin_amdgcn_mfma_f32_16x16x32_bf16(aF[mt][2], bF[0], c, 0,0,0);
          c = __builtin_amdgcn_mfma_f32_16x16x32_bf16(aF[mt][1], bF[1], c, 0,0,0);
          c = __builtin_amdgcn_mfma_f32_16x16x32_bf16(aF[mt][0], bF[2], c, 0,0,0);
        }
        c = __builtin_amdgcn_mfma_f32_16x16x32_bf16(aF[mt][1], bF[0], c, 0,0,0);
        c = __builtin_amdgcn_mfma_f32_16x16x32_bf16(aF[mt][0], bF[1], c, 0,0,0);
        c = __builtin_amdgcn_mfma_f32_16x16x32_bf16(aF[mt][0], bF[0], c, 0,0,0);
        acc[mt][nt] = c;
      }
    }
  }

  __syncthreads();
#pragma unroll
  for (int half = 0; half < 2; ++half) {
    if (wm == half) {
#pragma unroll
      for (int nt=0;nt<4;++nt) {
        int cl = wn*64 + nt*16 + fr;
        float bb = bias ? bias[bn*128 + cl] : 0.f;
#pragma unroll
        for (int mt=0;mt<4;++mt) {
          int r0 = mt*16 + (lane>>4)*4;
#pragma unroll
          for (int j=0;j<4;++j) {
            float vv = acc[mt][nt][j] + bb;
            if (ACT==1) vv = gelu_f(vv);
            sE[(r0+j)*132 + cl] = vv;
          }
        }
      }
    }
    __syncthreads();
#pragma unroll
    for (int it=0; it<8; ++it) {
      int idx = it*256 + tid;
      int rr = idx >> 5, c4 = (idx & 31) * 4;
      float4 vv = *(const float4*)&sE[rr*132 + c4];
      *(float4*)(C + (size_t)(bm*128 + half*64 + rr)*N + bn*128 + c4) = vv;
    }
    __syncthreads();
  }
}

// ------------------------- split-bf16 MFMA GEMM, 256x128 (FF) --------------
// Halves W-plane traffic (W read Mb=64 times instead of 128). Each wave owns
// a 128x64 quadrant (8 m-tiles x 4 n-tiles). Same per-element MFMA order as
// gemm_mfma -> bitwise-identical results.
template<int SPLIT, int ACT>
__global__ __launch_bounds__(256, 2) void gemm_mfma256(
    const float* __restrict__ A, const unsigned short* __restrict__ Wt,
    const float* __restrict__ bias, float* __restrict__ C,
    int M, int N, int K)
{
  constexpr int RS = SPLIT*32 + 8;
  __shared__ __align__(16) unsigned short smem[384*RS];
  unsigned short* sA = smem;               // 256 rows
  unsigned short* sB = smem + 256*RS;      // 128 rows
  float* sE = (float*)smem;                // 64x132 epilogue staging

  int tid = threadIdx.x;
  int bm = blockIdx.x, bn = blockIdx.y;
  int lane = tid & 63, wave = tid >> 6;
  int wm = wave & 1, wn = wave >> 1;       // wm: 128-row half, wn: 64-col half
  int fr = lane & 15, fk = (lane >> 4) * 8;

  floatx4 acc[8][4];
#pragma unroll
  for (int i=0;i<8;++i)
#pragma unroll
    for (int j=0;j<4;++j) acc[i][j] = (floatx4){0.f,0.f,0.f,0.f};

  int row = tid >> 1, kseg = (tid & 1) * 16;
  const float* aSrc0 = A + (size_t)(bm*256 + row)*K + kseg;
  const float* aSrc1 = A + (size_t)(bm*256 + 128 + row)*K + kseg;
  const unsigned short* bSrc = Wt + (size_t)(bn*128 + row)*K + kseg;

  float4 av4[2][4];
  uint4 bv[SPLIT][2];
#pragma unroll
  for (int q=0;q<4;++q) {
    av4[0][q] = *(const float4*)(aSrc0 + q*4);
    av4[1][q] = *(const float4*)(aSrc1 + q*4);
  }
#pragma unroll
  for (int p=0;p<SPLIT;++p) {
    const unsigned short* bp = bSrc + (size_t)p*N*K;
    bv[p][0] = *(const uint4*)(bp);
    bv[p][1] = *(const uint4*)(bp + 8);
  }

  for (int k0 = 0; k0 < K; k0 += 32) {
    __syncthreads();
#pragma unroll
    for (int r2 = 0; r2 < 2; ++r2) {
      unsigned short us[SPLIT][16];
      const float* ff = (const float*)av4[r2];
#pragma unroll
      for (int i=0;i<16;++i) {
        float v = ff[i];
        unsigned short h0 = f2bf(v);
        float r = v - bf2f(h0);
        us[0][i] = h0;
        unsigned short h1 = f2bf(r);
        us[1][i] = h1;
        if (SPLIT==3) { float r2r = r - bf2f(h1); us[2][i] = f2bf(r2r); }
      }
#pragma unroll
      for (int p=0;p<SPLIT;++p) {
        uint4* d = (uint4*)&sA[(r2*128 + row)*RS + p*32 + kseg];
        d[0] = *(const uint4*)&us[p][0];
        d[1] = *(const uint4*)&us[p][8];
      }
    }
#pragma unroll
    for (int p=0;p<SPLIT;++p) {
      uint4* db = (uint4*)&sB[row*RS + p*32 + kseg];
      db[0] = bv[p][0];
      db[1] = bv[p][1];
    }
    __syncthreads();
    if (k0 + 32 < K) {
#pragma unroll
      for (int q=0;q<4;++q) {
        av4[0][q] = *(const float4*)(aSrc0 + k0 + 32 + q*4);
        av4[1][q] = *(const float4*)(aSrc1 + k0 + 32 + q*4);
      }
#pragma unroll
      for (int p=0;p<SPLIT;++p) {
        const unsigned short* bp = bSrc + (size_t)p*N*K + k0 + 32;
        bv[p][0] = *(const uint4*)(bp);
        bv[p][1] = *(const uint4*)(bp + 8);
      }
    }

    // nt processed in 2 pairs to bound live registers
#pragma unroll
    for (int np = 0; np < 2; ++np) {
      bf16x8 bF[2][SPLIT];
#pragma unroll
      for (int n2=0;n2<2;++n2)
#pragma unroll
        for (int p=0;p<SPLIT;++p)
          bF[n2][p] = *(const bf16x8*)&sB[(wn*64 + (np*2+n2)*16 + fr)*RS + p*32 + fk];
#pragma unroll
      for (int mt=0; mt<8; ++mt) {
        bf16x8 aF[SPLIT];
#pragma unroll
        for (int p=0;p<SPLIT;++p)
          aF[p] = *(const bf16x8*)&sA[(wm*128 + mt*16 + fr)*RS + p*32 + fk];
#pragma unroll
        for (int n2=0;n2<2;++n2) {
          int nt = np*2 + n2;
          floatx4 c = acc[mt][nt];
          if (SPLIT==3) {
            c = __builtin_amdgcn_mfma_f32_16x16x32_bf16(aF[2], bF[n2][0], c, 0,0,0);
            c = __builtin_amdgcn_mfma_f32_16x16x32_bf16(aF[1], bF[n2][1], c, 0,0,0);
            c = __builtin_amdgcn_mfma_f32_16x16x32_bf16(aF[0], bF[n2][2], c, 0,0,0);
          }
          c = __builtin_amdgcn_mfma_f32_16x16x32_bf16(aF[1], bF[n2][0], c, 0,0,0);
          c = __builtin_amdgcn_mfma_f32_16x16x32_bf16(aF[0], bF[n2][1], c, 0,0,0);
          c = __builtin_amdgcn_mfma_f32_16x16x32_bf16(aF[0], bF[n2][0], c, 0,0,0);
          acc[mt][nt] = c;
        }
      }
    }
  }

  // epilogue: 4 quarters of 64 rows, staged through LDS, coalesced stores
  __syncthreads();
#pragma unroll
  for (int q = 0; q < 4; ++q) {
    if (wm == (q >> 1)) {
#pragma unroll
      for (int nt=0;nt<4;++nt) {
        int cl = wn*64 + nt*16 + fr;
        float bb = bias ? bias[bn*128 + cl] : 0.f;
#pragma unroll
        for (int mtl=0;mtl<4;++mtl) {
          int mt = (q & 1)*4 + mtl;
          int r0 = mtl*16 + (lane>>4)*4;
#pragma unroll
          for (int j=0;j<4;++j) {
            float vv = acc[mt][nt][j] + bb;
            if (ACT==1) vv = gelu_f(vv);
            sE[(r0+j)*132 + cl] = vv;
          }
        }
      }
    }
    __syncthreads();
#pragma unroll
    for (int it=0; it<8; ++it) {
      int idx = it*256 + tid;
      int rr = idx >> 5, c4 = (idx & 31) * 4;
      float4 vv = *(const float4*)&sE[rr*132 + c4];
      *(float4*)(C + (size_t)(bm*256 + q*64 + rr)*N + bn*128 + c4) = vv;
    }
    __syncthreads();
  }
}

// ------------------------- LSH hashing (fp64 accumulate) -------------------
__global__ __launch_bounds__(256) void hash_kernel(
    const float* __restrict__ qk, const float* __restrict__ rot,
    unsigned char* __restrict__ buckets)
{
  __shared__ float q[2][64];
  __shared__ double rv[2][128];
  int half = threadIdx.x >> 7;
  int lt = threadIdx.x & 127;
  int g = blockIdx.x*2 + half;
  int bh = g >> 12, t = g & 4095;
  int b = bh >> 3, hd = bh & 7;
  if (lt < 64)
    q[half][lt] = qk[((size_t)(b*4096 + t))*512 + hd*64 + lt];
  __syncthreads();
  double acc = 0.0;
#pragma unroll 8
  for (int f=0; f<64; ++f) acc += (double)q[half][f] * (double)rot[f*128 + lt];
  rv[half][lt] = acc;
  __syncthreads();
  if (lt < 4) {
    const double* r = &rv[half][lt*32];
    double best = r[0]; int bi = 0;
#pragma unroll
    for (int j=1; j<64; ++j) {
      double v = (j < 32) ? r[j] : -r[j-32];
      if (v > best) { best = v; bi = j; }
    }
    buckets[((size_t)(bh*4 + lt))*4096 + t] = (unsigned char)bi;
  }
}

// ------------------------- stable counting sort per (bh, round) ------------
__global__ __launch_bounds__(64) void sort_kernel(
    const unsigned char* __restrict__ buckets, int* __restrict__ st)
{
  __shared__ unsigned char sb[4096];
  __shared__ int cnts[64];
  int tid = threadIdx.x;
  const unsigned int* src4 = (const unsigned int*)(buckets + (size_t)blockIdx.x*4096);
  unsigned int* sb4 = (unsigned int*)sb;
  for (int i=tid; i<1024; i+=64) sb4[i] = src4[i];
  __syncthreads();
  unsigned int me = (unsigned int)tid;
  int cnt = 0;
  for (int t4=0; t4<1024; ++t4) {
    unsigned int w = sb4[t4];
    cnt += ((w & 255u) == me) + (((w>>8)&255u) == me)
         + (((w>>16)&255u) == me) + ((w>>24) == me);
  }
  cnts[tid] = cnt;
  __syncthreads();
  int base = 0;
  for (int j=0;j<tid;++j) base += cnts[j];
  int* dst = st + (size_t)blockIdx.x*4096;
  for (int t4=0; t4<1024; ++t4) {
    unsigned int w = sb4[t4];
#pragma unroll
    for (int q=0;q<4;++q)
      if (((w >> (8*q)) & 255u) == me) dst[base++] = t4*4 + q;
  }
}

// ------------------------- chunked attention, MFMA -------------------------
template<int SQ>
__global__ __launch_bounds__(256) void attn_mfma(
    const float* __restrict__ qk, const float* __restrict__ v,
    const int* __restrict__ st, float* __restrict__ osc,
    float* __restrict__ logits)
{
  constexpr int RQ = 72;
  constexpr int RP = 136;
  constexpr int QKE = SQ*128*RQ;
  constexpr int PVE = 2*64*RP*2;
  constexpr int UE = (QKE > PVE ? QKE : PVE);
  __shared__ __align__(16) unsigned short uni[UE];
  __shared__ int sPos[128];
  __shared__ float sInv[128];
  unsigned short* sQK = uni;
  unsigned short* sP  = uni;
  unsigned short* sVT = uni + 2*64*RP;

  int tid = threadIdx.x;
  int bh = blockIdx.x >> 8;
  int c  = blockIdx.x & 255;
  int b = bh >> 3, hd = bh & 7;
  int r = c >> 6;
  int lane = tid & 63, wave = tid >> 6;
  int fr = lane & 15, fq = lane >> 4;
  int fk = fq * 8;

  if (tid < 128) {
    int cprev = (c + 255) & 255;
    int slot = (tid < 64) ? (c*64 + tid) : (cprev*64 + tid - 64);
    sPos[tid] = st[bh*16384 + slot];
  }
  __syncthreads();

  int row = tid >> 1, ks2 = (tid & 1) * 32;
  float vreg[32];
  {
    size_t rbase = ((size_t)(b*4096 + sPos[row]))*512 + hd*64 + ks2;
    const float* src  = qk + rbase;
    const float* vsrc = v  + rbase;
    float qreg[32];
    float ss = 0.f;
#pragma unroll
    for (int i=0;i<32;i+=4) {
      float4 x = *(const float4*)(src + i);
      qreg[i]=x.x; qreg[i+1]=x.y; qreg[i+2]=x.z; qreg[i+3]=x.w;
      ss += x.x*x.x + x.y*x.y + x.z*x.z + x.w*x.w;
      float4 y = *(const float4*)(vsrc + i);
      vreg[i]=y.x; vreg[i+1]=y.y; vreg[i+2]=y.z; vreg[i+3]=y.w;
    }
    ss += __shfl_xor(ss, 1, 64);
    if ((tid & 1) == 0) sInv[row] = 1.0f / fmaxf(sqrtf(ss), 1e-12f);
    unsigned short us[3][32];
#pragma unroll
    for (int i=0;i<32;++i) {
      float vv = qreg[i];
      unsigned short h0 = f2bf(vv);
      float r1 = vv - bf2f(h0);
      unsigned short h1 = f2bf(r1);
      us[0][i] = h0; us[1][i] = h1;
      if (SQ==3) { float r2 = r1 - bf2f(h1); us[2][i] = f2bf(r2); }
    }
#pragma unroll
    for (int p=0;p<SQ;++p) {
      uint4* d = (uint4*)&sQK[p*128*RQ + row*RQ + ks2];
      d[0] = *(const uint4*)&us[p][0];
      d[1] = *(const uint4*)&us[p][8];
      d[2] = *(const uint4*)&us[p][16];
      d[3] = *(const uint4*)&us[p][24];
    }
  }
  __syncthreads();

  floatx4 s[8];
#pragma unroll
  for (int nt=0;nt<8;++nt) s[nt] = (floatx4){0.f,0.f,0.f,0.f};
#pragma unroll
  for (int ks=0; ks<2; ++ks) {
    bf16x8 aQ[SQ];
#pragma unroll
    for (int p=0;p<SQ;++p)
      aQ[p] = *(const bf16x8*)&sQK[p*128*RQ + (wave*16 + fr)*RQ + ks*32 + fk];
#pragma unroll
    for (int nt=0;nt<8;++nt) {
      bf16x8 bK[SQ];
#pragma unroll
      for (int p=0;p<SQ;++p)
        bK[p] = *(const bf16x8*)&sQK[p*128*RQ + (nt*16 + fr)*RQ + ks*32 + fk];
      floatx4 cc = s[nt];
      if (SQ==3) {
        cc = __builtin_amdgcn_mfma_f32_16x16x32_bf16(aQ[2], bK[0], cc, 0,0,0);
        cc = __builtin_amdgcn_mfma_f32_16x16x32_bf16(aQ[1], bK[1], cc, 0,0,0);
        cc = __builtin_amdgcn_mfma_f32_16x16x32_bf16(aQ[0], bK[2], cc, 0,0,0);
      }
      cc = __builtin_amdgcn_mfma_f32_16x16x32_bf16(aQ[1], bK[0], cc, 0,0,0);
      cc = __builtin_amdgcn_mfma_f32_16x16x32_bf16(aQ[0], bK[1], cc, 0,0,0);
      cc = __builtin_amdgcn_mfma_f32_16x16x32_bf16(aQ[0], bK[0], cc, 0,0,0);
      s[nt] = cc;
    }
  }

  int ipos[4];
#pragma unroll
  for (int reg=0;reg<4;++reg) ipos[reg] = sPos[wave*16 + fq*4 + reg];
  float dv[8][4];
  float mx[4] = {-1e30f,-1e30f,-1e30f,-1e30f};
#pragma unroll
  for (int nt=0;nt<8;++nt) {
    float invj = sInv[nt*16 + fr];
    int jpos = sPos[nt*16 + fr];
#pragma unroll
    for (int reg=0;reg<4;++reg) {
      float d = s[nt][reg] * invj * 0.125f;
      if (jpos == ipos[reg]) d = -5.0e4f;
      dv[nt][reg] = d;
      mx[reg] = fmaxf(mx[reg], d);
    }
  }
#pragma unroll
  for (int reg=0;reg<4;++reg) {
    mx[reg] = fmaxf(mx[reg], __shfl_xor(mx[reg], 1, 64));
    mx[reg] = fmaxf(mx[reg], __shfl_xor(mx[reg], 2, 64));
    mx[reg] = fmaxf(mx[reg], __shfl_xor(mx[reg], 4, 64));
    mx[reg] = fmaxf(mx[reg], __shfl_xor(mx[reg], 8, 64));
  }
  float sum[4] = {0.f,0.f,0.f,0.f};
#pragma unroll
  for (int nt=0;nt<8;++nt)
#pragma unroll
    for (int reg=0;reg<4;++reg) sum[reg] += expf(dv[nt][reg] - mx[reg]);
  float lse[4];
#pragma unroll
  for (int reg=0;reg<4;++reg) {
    sum[reg] += __shfl_xor(sum[reg], 1, 64);
    sum[reg] += __shfl_xor(sum[reg], 2, 64);
    sum[reg] += __shfl_xor(sum[reg], 4, 64);
    sum[reg] += __shfl_xor(sum[reg], 8, 64);
    lse[reg] = mx[reg] + logf(sum[reg]);
  }
  if (fr == 0) {
#pragma unroll
    for (int reg=0;reg<4;++reg)
      logits[((size_t)(bh*4 + r))*4096 + ipos[reg]] = lse[reg];
  }
#pragma unroll
  for (int nt=0;nt<8;++nt)
#pragma unroll
    for (int reg=0;reg<4;++reg) dv[nt][reg] = expf(dv[nt][reg] - lse[reg]);

  __syncthreads();

#pragma unroll
  for (int nt=0;nt<8;++nt) {
    int key = nt*16 + fr;
#pragma unroll
    for (int reg=0;reg<4;++reg) {
      int m = wave*16 + fq*4 + reg;
      float p = dv[nt][reg];
      unsigned short h0 = f2bf(p);
      sP[0*64*RP + m*RP + key] = h0;
      sP[1*64*RP + m*RP + key] = f2bf(p - bf2f(h0));
    }
  }
#pragma unroll
  for (int i=0;i<32;++i) {
    int dh = ks2 + i;
    float vv = vreg[i];
    unsigned short h0 = f2bf(vv);
    sVT[0*64*RP + dh*RP + row] = h0;
    sVT[1*64*RP + dh*RP + row] = f2bf(vv - bf2f(h0));
  }
  __syncthreads();

  size_t obase = ((size_t)(bh*4 + r)) * 4096;
#pragma unroll
  for (int dt=0;dt<4;++dt) {
    floatx4 o = (floatx4){0.f,0.f,0.f,0.f};
#pragma unroll
    for (int ks=0; ks<4; ++ks) {
      bf16x8 aP0 = *(const bf16x8*)&sP[0*64*RP + (wave*16 + fr)*RP + ks*32 + fk];
      bf16x8 aP1 = *(const bf16x8*)&sP[1*64*RP + (wave*16 + fr)*RP + ks*32 + fk];
      bf16x8 bV0 = *(const bf16x8*)&sVT[0*64*RP + (dt*16 + fr)*RP + ks*32 + fk];
      bf16x8 bV1 = *(const bf16x8*)&sVT[1*64*RP + (dt*16 + fr)*RP + ks*32 + fk];
      o = __builtin_amdgcn_mfma_f32_16x16x32_bf16(aP1, bV1, o, 0,0,0);
      o = __builtin_amdgcn_mfma_f32_16x16x32_bf16(aP1, bV0, o, 0,0,0);
      o = __builtin_amdgcn_mfma_f32_16x16x32_bf16(aP0, bV1, o, 0,0,0);
      o = __builtin_amdgcn_mfma_f32_16x16x32_bf16(aP0, bV0, o, 0,0,0);
    }
    int dh = dt*16 + fr;
#pragma unroll
    for (int reg=0;reg<4;++reg) {
      int m = wave*16 + fq*4 + reg;
      osc[(obase + sPos[m])*64 + dh] = o[reg];
    }
  }
}

// ------------------------- combine rounds + merge heads --------------------
__global__ __launch_bounds__(256) void combine_kernel(
    const float* __restrict__ osc, const float* __restrict__ logits,
    float* __restrict__ merged)
{
  int idx = blockIdx.x;
  int b = idx >> 12, t = idx & 4095;
  int tid = threadIdx.x;
  __shared__ float w[8][4];
  if (tid < 8) {
    size_t lbase = ((size_t)(b*8 + tid)) * 4 * 4096 + t;
    float l0 = logits[lbase], l1 = logits[lbase + 4096],
          l2 = logits[lbase + 8192], l3 = logits[lbase + 12288];
    float m = fmaxf(fmaxf(l0,l1), fmaxf(l2,l3));
    float e0 = expf(l0-m), e1 = expf(l1-m), e2 = expf(l2-m), e3 = expf(l3-m);
    float inv = 1.0f/(e0+e1+e2+e3);
    w[tid][0]=e0*inv; w[tid][1]=e1*inv; w[tid][2]=e2*inv; w[tid][3]=e3*inv;
  }
  __syncthreads();
#pragma unroll
  for (int rep=0; rep<2; ++rep) {
    int d = tid + rep*256;
    int hd = d >> 6, dh = d & 63;
    size_t obase = (((size_t)(b*8 + hd)) * 4 * 4096 + t) * 64 + dh;
    float o = w[hd][0]*osc[obase]
            + w[hd][1]*osc[obase + 262144]
            + w[hd][2]*osc[obase + 524288]
            + w[hd][3]*osc[obase + 786432];
    merged[(size_t)idx*512 + d] = o;
  }
}

// ------------------------- residual + LayerNorm (in-place on h) ------------
__global__ __launch_bounds__(256) void ln_residual_kernel(
    float* __restrict__ h, const float* __restrict__ a,
    const float* __restrict__ g, const float* __restrict__ bb)
{
  int row = blockIdx.x;
  int tid = threadIdx.x;
  size_t base = (size_t)row * 512;
  float x0 = h[base + tid]       + a[base + tid];
  float x1 = h[base + tid + 256] + a[base + tid + 256];
  float s  = x0 + x1;
  float sq = x0*x0 + x1*x1;
#pragma unroll
  for (int off = 32; off > 0; off >>= 1) {
    s  += __shfl_down(s, off, 64);
    sq += __shfl_down(sq, off, 64);
  }
  __shared__ float rs[4], rq[4], sm[2];
  int wv = tid >> 6;
  if ((tid & 63) == 0) { rs[wv] = s; rq[wv] = sq; }
  __syncthreads();
  if (tid == 0) {
    float S = rs[0]+rs[1]+rs[2]+rs[3];
    float Q = rq[0]+rq[1]+rq[2]+rq[3];
    float m = S * (1.0f/512.0f);
    float var = Q * (1.0f/512.0f) - m*m;
    sm[0] = m; sm[1] = rsqrtf(var + 1e-5f);
  }
  __syncthreads();
  float m = sm[0], rstd = sm[1];
  h[base + tid]       = (x0 - m) * rstd * g[tid]       + bb[tid];
  h[base + tid + 256] = (x1 - m) * rstd * g[tid + 256] + bb[tid + 256];
}

// ------------------------- final LN + projection ---------------------------
__global__ __launch_bounds__(256) void final_kernel(
    const float* __restrict__ h, const float* __restrict__ g, const float* __restrict__ bb,
    const float* __restrict__ Wp, const float* __restrict__ bp, float* __restrict__ out)
{
  int idx = blockIdx.x;
  int b = idx >> 9, tp = idx & 511;
  size_t base = ((size_t)(b*4096 + 3584 + tp)) * 512;
  int tid = threadIdx.x;
  float x0 = h[base + tid], x1 = h[base + tid + 256];
  float s = x0 + x1, sq = x0*x0 + x1*x1;
#pragma unroll
  for (int off = 32; off > 0; off >>= 1) {
    s  += __shfl_down(s, off, 64);
    sq += __shfl_down(sq, off, 64);
  }
  __shared__ float rs[4], rq[4], sm[2];
  int wv = tid >> 6;
  if ((tid & 63) == 0) { rs[wv] = s; rq[wv] = sq; }
  __syncthreads();
  if (tid == 0) {
    float S = rs[0]+rs[1]+rs[2]+rs[3];
    float Q = rq[0]+rq[1]+rq[2]+rq[3];
    float m = S*(1.f/512.f);
    float var = Q*(1.f/512.f) - m*m;
    sm[0]=m; sm[1]=rsqrtf(var+1e-5f);
  }
  __syncthreads();
  __shared__ float xn[512];
  float m = sm[0], rstd = sm[1];
  xn[tid]     = (x0-m)*rstd*g[tid]     + bb[tid];
  xn[tid+256] = (x1-m)*rstd*g[tid+256] + bb[tid+256];
  __syncthreads();
  if (tid < 224) {
    int col = tid >> 5, lane = tid & 31;
    float p = 0.f;
    for (int f = lane; f < 512; f += 32) p += xn[f]*Wp[f*7 + col];
#pragma unroll
    for (int off=16; off>0; off>>=1) p += __shfl_down(p, off, 32);
    if (lane == 0) out[(size_t)idx*7 + col] = p + bp[col];
  }
}

// ---------------------------------------------------------------------------
extern "C" void kernel_launch(void* const* d_in, const int* in_sizes, int n_in,
                              void* d_out, int out_size, void* d_ws, size_t ws_size,
                              hipStream_t stream)
{
  (void)in_sizes; (void)n_in; (void)out_size; (void)ws_size;
  const float* x_enc  = (const float*)d_in[0];
  const float* x_dec  = (const float*)d_in[1];
  const int*   xm_enc = (const int*)d_in[2];
  const int*   xm_dec = (const int*)d_in[3];
  const float* conv_w = (const float*)d_in[4];
  const float* month  = (const float*)d_in[5];
  const float* day    = (const float*)d_in[6];
  const float* wday   = (const float*)d_in[7];
  const float* hourE  = (const float*)d_in[8];
  const float* minE   = (const float*)d_in[9];
  const float* W_qk   = (const float*)d_in[10];
  const float* W_v    = (const float*)d_in[11];
  const float* W_out  = (const float*)d_in[12];
  const float* b_out  = (const float*)d_in[13];
  const float* rots   = (const float*)d_in[14];
  const float* ln1_g  = (const float*)d_in[15];
  const float* ln1_b  = (const float*)d_in[16];
  const float* W_ff1  = (const float*)d_in[17];
  const float* b_ff1  = (const float*)d_in[18];
  const float* W_ff2  = (const float*)d_in[19];
  const float* b_ff2  = (const float*)d_in[20];
  const float* ln2_g  = (const float*)d_in[21];
  const float* ln2_b  = (const float*)d_in[22];
  const float* lnf_g  = (const float*)d_in[23];
  const float* lnf_b  = (const float*)d_in[24];
  const float* W_proj = (const float*)d_in[25];
  const float* b_proj = (const float*)d_in[26];

  float* h    = (float*)d_ws;            // 8M floats
  float* bufA = h    + 8388608ull;       // 8M
  float* bufB = bufA + 8388608ull;       // 8M
  float* osc  = bufB + 8388608ull;       // 32M (attn out / FFN mid / pe / Wt)
  float* lg   = osc  + 33554432ull;      // 512K
  int*   stp  = (int*)(lg + 524288ull);  // 512K ints
  unsigned char* bkt = (unsigned char*)(stp + 524288ull); // 512KB
  float* pe   = osc;                     // only live during embed
  unsigned short* WtA = (unsigned short*)osc;   // Wt for v/out (osc dead then)
  unsigned short* WtB = (unsigned short*)bufB;  // Wt for ff1/ff2 (bufB dead then)

  pe_kernel<<<4096, 256, 0, stream>>>(pe);
  embed_kernel<<<16384, 256, 0, stream>>>(x_enc, x_dec, xm_enc, xm_dec, conv_w,
                                          month, day, wday, hourE, minE, pe, h);
  for (int l = 0; l < 2; ++l) {
    const float* Wqk = W_qk + (size_t)l*262144;
    const float* Wv  = W_v  + (size_t)l*262144;
    const float* Wo  = W_out+ (size_t)l*262144;
    const float* Wf1 = W_ff1 + (size_t)l*1048576;
    const float* Wf2 = W_ff2 + (size_t)l*1048576;
    const float* rot = rots + (size_t)l*8192;

    // qk projection: precise (feeds LSH argmax directly)
    gemm_kernel<0><<<dim3(128,4), 256, 0, stream>>>(h, Wqk, nullptr, bufA, 16384, 512, 512);
    // v projection: split-bf16 MFMA (x3 on layer 0, x2 on layer 1)
    if (l == 0) {
      wsplit_kernel<3><<<dim3(16,16), 256, 0, stream>>>(Wv, WtA, 512, 512);
      gemm_mfma<3,0><<<dim3(128,4), 256, 0, stream>>>(h, WtA, nullptr, bufB, 16384, 512, 512);
    } else {
      wsplit_kernel<2><<<dim3(16,16), 256, 0, stream>>>(Wv, WtA, 512, 512);
      gemm_mfma<2,0><<<dim3(128,4), 256, 0, stream>>>(h, WtA, nullptr, bufB, 16384, 512, 512);
    }
    hash_kernel<<<65536, 256, 0, stream>>>(bufA, rot, bkt);
    sort_kernel<<<128, 64, 0, stream>>>(bkt, stp);
    if (l == 0)
      attn_mfma<3><<<8192, 256, 0, stream>>>(bufA, bufB, stp, osc, lg);
    else
      attn_mfma<2><<<8192, 256, 0, stream>>>(bufA, bufB, stp, osc, lg);
    combine_kernel<<<16384, 256, 0, stream>>>(osc, lg, bufA);
    // out projection
    if (l == 0) {
      wsplit_kernel<3><<<dim3(16,16), 256, 0, stream>>>(Wo, WtA, 512, 512);
      gemm_mfma<3,0><<<dim3(128,4), 256, 0, stream>>>(bufA, WtA, b_out + l*512, bufB, 16384, 512, 512);
    } else {
      wsplit_kernel<2><<<dim3(16,16), 256, 0, stream>>>(Wo, WtA, 512, 512);
      gemm_mfma<2,0><<<dim3(128,4), 256, 0, stream>>>(bufA, WtA, b_out + l*512, bufB, 16384, 512, 512);
    }
    ln_residual_kernel<<<16384, 256, 0, stream>>>(h, bufB, ln1_g + l*512, ln1_b + l*512);
    // FFN (256x128 tile: halves W-plane staging traffic)
    if (l == 0) {
      wsplit_kernel<3><<<dim3(16,64), 256, 0, stream>>>(Wf1, WtB, 512, 2048);
      gemm_mfma256<3,1><<<dim3(64,16), 256, 0, stream>>>(h, WtB, b_ff1 + l*2048, osc, 16384, 2048, 512);
      wsplit_kernel<3><<<dim3(64,16), 256, 0, stream>>>(Wf2, WtB, 2048, 512);
      gemm_mfma256<3,0><<<dim3(64,4), 256, 0, stream>>>(osc, WtB, b_ff2 + l*512, bufA, 16384, 512, 2048);
    } else {
      wsplit_kernel<2><<<dim3(16,64), 256, 0, stream>>>(Wf1, WtB, 512, 2048);
      gemm_mfma256<2,1><<<dim3(64,16), 256, 0, stream>>>(h, WtB, b_ff1 + l*2048, osc, 16384, 2048, 512);
      wsplit_kernel<2><<<dim3(64,16), 256, 0, stream>>>(Wf2, WtB, 2048, 512);
      gemm_mfma256<2,0><<<dim3(64,4), 256, 0, stream>>>(osc, WtB, b_ff2 + l*512, bufA, 16384, 512, 2048);
    }
    ln_residual_kernel<<<16384, 256, 0, stream>>>(h, bufA, ln2_g + l*512, ln2_b + l*512);
  }
  final_kernel<<<2048, 256, 0, stream>>>(h, lnf_g, lnf_b, W_proj, b_proj, (float*)d_out);
}

// Round 11
// 3358.949 us; speedup vs baseline: 1.3392x; 1.0845x over previous
//
#include <hip/hip_runtime.h>
#include <math.h>

// ---------------------------------------------------------------------------
// Reformer forward. BEST CONFIG (round 8: 3326 us) — reverted from rounds 9
// (2-deep prefetch: FETCH x4, memory-bound, 4498) and 10 (256-tile FF:
// occupancy 12->8 waves/CU + write amplification, 3643).
// GEMMs v/out/ff: in-kernel split-bf16 MFMA (3-way l0 -> feeds l1 LSH hash;
// 2-way l1). QK projections fp32+fp64-acc (feed LSH argmax). Attention:
// MFMA (l0 3-plane Q/K, l1 2-plane; P/V 2-plane).
// B=4, L=4096, D=512, H=8, DH=64, FF=2048, EL=2, BS=64, NHASH=4
// ---------------------------------------------------------------------------

typedef __attribute__((ext_vector_type(8))) __bf16 bf16x8;
typedef __attribute__((ext_vector_type(4))) float floatx4;

__device__ __forceinline__ unsigned short f2bf(float f) {
  union { float f; unsigned int u; } x; x.f = f;
  unsigned int r = x.u + 0x7fffu + ((x.u >> 16) & 1u);
  return (unsigned short)(r >> 16);
}
__device__ __forceinline__ float bf2f(unsigned short u) {
  union { unsigned int u; float f; } x; x.u = ((unsigned int)u) << 16;
  return x.f;
}
__device__ __forceinline__ float gelu_f(float x) {
  return 0.5f * x * (1.0f + erff(x * 0.70710678118654752440f));
}

// ------------------------- positional-encoding table -----------------------
__global__ __launch_bounds__(256) void pe_kernel(float* __restrict__ pe)
{
  int t = blockIdx.x;
#pragma unroll
  for (int rep = 0; rep < 2; ++rep) {
    int d = threadIdx.x + rep * 256;
    float cf = (float)(-9.210340371976184 / 512.0);
    float xf = (float)(d & ~1) * cf;
    float freq = (float)exp((double)xf);
    float angf = (float)t * freq;
    double a = (double)angf;
    pe[t * 512 + d] = (float)((d & 1) ? cos(a) : sin(a));
  }
}

// ------------------------- embedding ---------------------------------------
__global__ __launch_bounds__(256) void embed_kernel(
    const float* __restrict__ x_enc, const float* __restrict__ x_dec,
    const int* __restrict__ xm_enc, const int* __restrict__ xm_dec,
    const float* __restrict__ conv_w,
    const float* __restrict__ month, const float* __restrict__ day,
    const float* __restrict__ wday, const float* __restrict__ hour,
    const float* __restrict__ minute, const float* __restrict__ pe,
    float* __restrict__ h)
{
  int idx = blockIdx.x;
  int b = idx >> 12, t = idx & 4095;
  __shared__ float xv[21];
  __shared__ int mi[5];
  int tid = threadIdx.x;
  if (tid < 21) {
    int w = tid / 7, c = tid % 7;
    int s = (t + w + 4095) & 4095;
    xv[tid] = (s < 3584) ? x_enc[(s + b*3584)*7 + c]
                         : x_dec[((s - 3584) + b*512)*7 + c];
  }
  if (tid >= 32 && tid < 37) {
    int j = tid - 32;
    mi[j] = (t < 3584) ? xm_enc[(b*3584 + t)*5 + j]
                       : xm_dec[(b*512 + (t - 3584))*5 + j];
  }
  __syncthreads();
  int m0 = mi[0], m1 = mi[1], m2 = mi[2], m3 = mi[3], m4 = mi[4];
#pragma unroll
  for (int rep = 0; rep < 2; ++rep) {
    int d = tid + rep*256;
    float tok = 0.f;
#pragma unroll
    for (int wc = 0; wc < 21; ++wc) tok += xv[wc] * conv_w[wc*512 + d];
    float temp = month[m0*512+d] + day[m1*512+d] + wday[m2*512+d]
               + hour[m3*512+d] + minute[m4*512+d];
    h[(size_t)idx*512 + d] = tok + temp + pe[t*512 + d];
  }
}

// ------------------------- precise fp32 GEMM (QK projections only) ---------
template<int ACT>
__global__ __launch_bounds__(256) void gemm_kernel(
    const float* __restrict__ A, const float* __restrict__ W,
    const float* __restrict__ bias, float* __restrict__ C,
    int M, int N, int K)
{
  __shared__ float As[8][132];
  __shared__ float Bs[8][132];
  int tid = threadIdx.x;
  int bm = blockIdx.x, bn = blockIdx.y;
  int tr = tid >> 4, tc = tid & 15;
  double acc[8][8];
  float tt[8][8];
#pragma unroll
  for (int i=0;i<8;++i)
#pragma unroll
    for (int j=0;j<8;++j) { acc[i][j]=0.0; tt[i][j]=0.f; }

  int am  = tid >> 1;
  int at  = (tid & 1) * 4;
  int bkr = tid >> 5;
  int bn4 = (tid & 31) * 4;
  const float* Aptr = A + (size_t)(bm*128 + am)*K + at;
  const float* Bptr = W + (size_t)bkr*N + bn*128 + bn4;

  int phase = 0;
  for (int k0 = 0; k0 < K; k0 += 8) {
    float4 a4 = *(const float4*)(Aptr + k0);
    float4 b4 = *(const float4*)(Bptr + (size_t)k0*N);
    __syncthreads();
    As[at+0][am] = a4.x; As[at+1][am] = a4.y;
    As[at+2][am] = a4.z; As[at+3][am] = a4.w;
    *(float4*)&Bs[bkr][bn4] = b4;
    __syncthreads();
#pragma unroll
    for (int k=0;k<8;++k) {
      float4 a0 = *(const float4*)&As[k][tr*8];
      float4 a1 = *(const float4*)&As[k][tr*8+4];
      float4 b0 = *(const float4*)&Bs[k][tc*8];
      float4 b1 = *(const float4*)&Bs[k][tc*8+4];
      float av[8] = {a0.x,a0.y,a0.z,a0.w,a1.x,a1.y,a1.z,a1.w};
      float bv[8] = {b0.x,b0.y,b0.z,b0.w,b1.x,b1.y,b1.z,b1.w};
#pragma unroll
      for (int i=0;i<8;++i)
#pragma unroll
        for (int j=0;j<8;++j) tt[i][j] += av[i]*bv[j];
    }
    phase ^= 1;
    if (!phase) {
#pragma unroll
      for (int i=0;i<8;++i)
#pragma unroll
        for (int j=0;j<8;++j) { acc[i][j] += (double)tt[i][j]; tt[i][j]=0.f; }
    }
  }
  int row0 = bm*128 + tr*8;
  int col0 = bn*128 + tc*8;
  float bvb[8];
#pragma unroll
  for (int j=0;j<8;++j) bvb[j] = bias ? bias[col0+j] : 0.f;
#pragma unroll
  for (int i=0;i<8;++i) {
    float o[8];
#pragma unroll
    for (int j=0;j<8;++j) {
      float vv = (float)acc[i][j] + bvb[j];
      if (ACT==1) vv = gelu_f(vv);
      o[j] = vv;
    }
    float4* dst = (float4*)(C + (size_t)(row0+i)*N + col0);
    dst[0] = make_float4(o[0],o[1],o[2],o[3]);
    dst[1] = make_float4(o[4],o[5],o[6],o[7]);
  }
}

// ------------------------- weight transpose + bf16 split prepass -----------
// W: [K][N] fp32 -> Wt planes: [p][N][K] bf16 (k-contiguous for MFMA frags)
template<int SPLIT>
__global__ __launch_bounds__(256) void wsplit_kernel(
    const float* __restrict__ W, unsigned short* __restrict__ Wt, int K, int N)
{
  __shared__ float tile[32][33];
  int k0 = blockIdx.x*32, n0 = blockIdx.y*32;
  int tid = threadIdx.x;
  int kk = tid >> 3, nn4 = (tid & 7)*4;
  float4 w4 = *(const float4*)(W + (size_t)(k0+kk)*N + n0 + nn4);
  tile[kk][nn4+0]=w4.x; tile[kk][nn4+1]=w4.y;
  tile[kk][nn4+2]=w4.z; tile[kk][nn4+3]=w4.w;
  __syncthreads();
  int n = tid >> 3, k4 = (tid & 7)*4;
  unsigned short o[3][4];
#pragma unroll
  for (int j=0;j<4;++j) {
    float v = tile[k4+j][n];
    unsigned short h0 = f2bf(v);
    float r = v - bf2f(h0);
    unsigned short h1 = f2bf(r);
    o[0][j] = h0; o[1][j] = h1;
    if (SPLIT==3) { float r2 = r - bf2f(h1); o[2][j] = f2bf(r2); }
  }
#pragma unroll
  for (int p=0;p<SPLIT;++p) {
    ushort4* d = (ushort4*)(Wt + (size_t)p*N*K + (size_t)(n0+n)*K + k0 + k4);
    *d = make_ushort4(o[p][0], o[p][1], o[p][2], o[p][3]);
  }
}

// ------------------------- split-bf16 MFMA GEMM (in-kernel A split) --------
// C = A(fp32 MxK) @ W(KxN, pre-split Wt planes), 128x128 tile, BK=32,
// 16x16x32 bf16 MFMA, 4 waves each computing a 64x64 quadrant.
template<int SPLIT, int ACT>
__global__ __launch_bounds__(256, 3) void gemm_mfma(
    const float* __restrict__ A, const unsigned short* __restrict__ Wt,
    const float* __restrict__ bias, float* __restrict__ C,
    int M, int N, int K)
{
  constexpr int RS = SPLIT*32 + 8;
  __shared__ __align__(16) unsigned short smem[2*128*RS];
  unsigned short* sA = smem;
  unsigned short* sB = smem + 128*RS;
  float* sE = (float*)smem;

  int tid = threadIdx.x;
  int bm = blockIdx.x, bn = blockIdx.y;
  int lane = tid & 63, wave = tid >> 6;
  int wm = wave & 1, wn = wave >> 1;
  int fr = lane & 15, fk = (lane >> 4) * 8;

  floatx4 acc[4][4];
#pragma unroll
  for (int i=0;i<4;++i)
#pragma unroll
    for (int j=0;j<4;++j) acc[i][j] = (floatx4){0.f,0.f,0.f,0.f};

  int row = tid >> 1, kseg = (tid & 1) * 16;
  const float* aSrc = A + (size_t)(bm*128 + row)*K + kseg;
  const unsigned short* bSrc = Wt + (size_t)(bn*128 + row)*K + kseg;

  float4 av4[4];
  uint4 bv[SPLIT][2];
#pragma unroll
  for (int q=0;q<4;++q) av4[q] = *(const float4*)(aSrc + q*4);
#pragma unroll
  for (int p=0;p<SPLIT;++p) {
    const unsigned short* bp = bSrc + (size_t)p*N*K;
    bv[p][0] = *(const uint4*)(bp);
    bv[p][1] = *(const uint4*)(bp + 8);
  }

  for (int k0 = 0; k0 < K; k0 += 32) {
    __syncthreads();
    unsigned short us[SPLIT][16];
    const float* ff = (const float*)av4;
#pragma unroll
    for (int i=0;i<16;++i) {
      float v = ff[i];
      unsigned short h0 = f2bf(v);
      float r = v - bf2f(h0);
      us[0][i] = h0;
      unsigned short h1 = f2bf(r);
      us[1][i] = h1;
      if (SPLIT==3) { float r2 = r - bf2f(h1); us[2][i] = f2bf(r2); }
    }
#pragma unroll
    for (int p=0;p<SPLIT;++p) {
      uint4* d = (uint4*)&sA[row*RS + p*32 + kseg];
      d[0] = *(const uint4*)&us[p][0];
      d[1] = *(const uint4*)&us[p][8];
      uint4* db = (uint4*)&sB[row*RS + p*32 + kseg];
      db[0] = bv[p][0];
      db[1] = bv[p][1];
    }
    __syncthreads();
    if (k0 + 32 < K) {
#pragma unroll
      for (int q=0;q<4;++q) av4[q] = *(const float4*)(aSrc + k0 + 32 + q*4);
#pragma unroll
      for (int p=0;p<SPLIT;++p) {
        const unsigned short* bp = bSrc + (size_t)p*N*K + k0 + 32;
        bv[p][0] = *(const uint4*)(bp);
        bv[p][1] = *(const uint4*)(bp + 8);
      }
    }

    bf16x8 aF[4][SPLIT];
#pragma unroll
    for (int mt=0;mt<4;++mt)
#pragma unroll
      for (int p=0;p<SPLIT;++p)
        aF[mt][p] = *(const bf16x8*)&sA[(wm*64 + mt*16 + fr)*RS + p*32 + fk];
#pragma unroll
    for (int nt=0;nt<4;++nt) {
      bf16x8 bF[SPLIT];
#pragma unroll
      for (int p=0;p<SPLIT;++p)
        bF[p] = *(const bf16x8*)&sB[(wn*64 + nt*16 + fr)*RS + p*32 + fk];
#pragma unroll
      for (int mt=0;mt<4;++mt) {
        floatx4 c = acc[mt][nt];
        if (SPLIT==3) {
          c = __builtin_amdgcn_mfma_f32_16x16x32_bf16(aF[mt][2], bF[0], c, 0,0,0);
          c = __builtin_amdgcn_mfma_f32_16x16x32_bf16(aF[mt][1], bF[1], c, 0,0,0);
          c = __builtin_amdgcn_mfma_f32_16x16x32_bf16(aF[mt][0], bF[2], c, 0,0,0);
        }
        c = __builtin_amdgcn_mfma_f32_16x16x32_bf16(aF[mt][1], bF[0], c, 0,0,0);
        c = __builtin_amdgcn_mfma_f32_16x16x32_bf16(aF[mt][0], bF[1], c, 0,0,0);
        c = __builtin_amdgcn_mfma_f32_16x16x32_bf16(aF[mt][0], bF[0], c, 0,0,0);
        acc[mt][nt] = c;
      }
    }
  }

  // epilogue: C/D layout col = lane&15, row = (lane>>4)*4 + reg  [m89]
  __syncthreads();
#pragma unroll
  for (int half = 0; half < 2; ++half) {
    if (wm == half) {
#pragma unroll
      for (int nt=0;nt<4;++nt) {
        int cl = wn*64 + nt*16 + fr;
        float bb = bias ? bias[bn*128 + cl] : 0.f;
#pragma unroll
        for (int mt=0;mt<4;++mt) {
          int r0 = mt*16 + (lane>>4)*4;
#pragma unroll
          for (int j=0;j<4;++j) {
            float vv = acc[mt][nt][j] + bb;
            if (ACT==1) vv = gelu_f(vv);
            sE[(r0+j)*132 + cl] = vv;
          }
        }
      }
    }
    __syncthreads();
#pragma unroll
    for (int it=0; it<8; ++it) {
      int idx = it*256 + tid;
      int rr = idx >> 5, c4 = (idx & 31) * 4;
      float4 vv = *(const float4*)&sE[rr*132 + c4];
      *(float4*)(C + (size_t)(bm*128 + half*64 + rr)*N + bn*128 + c4) = vv;
    }
    __syncthreads();
  }
}

// ------------------------- LSH hashing (fp64 accumulate) -------------------
__global__ __launch_bounds__(256) void hash_kernel(
    const float* __restrict__ qk, const float* __restrict__ rot,
    unsigned char* __restrict__ buckets)
{
  __shared__ float q[2][64];
  __shared__ double rv[2][128];
  int half = threadIdx.x >> 7;
  int lt = threadIdx.x & 127;
  int g = blockIdx.x*2 + half;
  int bh = g >> 12, t = g & 4095;
  int b = bh >> 3, hd = bh & 7;
  if (lt < 64)
    q[half][lt] = qk[((size_t)(b*4096 + t))*512 + hd*64 + lt];
  __syncthreads();
  double acc = 0.0;
#pragma unroll 8
  for (int f=0; f<64; ++f) acc += (double)q[half][f] * (double)rot[f*128 + lt];
  rv[half][lt] = acc;
  __syncthreads();
  if (lt < 4) {
    const double* r = &rv[half][lt*32];
    double best = r[0]; int bi = 0;
#pragma unroll
    for (int j=1; j<64; ++j) {
      double v = (j < 32) ? r[j] : -r[j-32];
      if (v > best) { best = v; bi = j; }
    }
    buckets[((size_t)(bh*4 + lt))*4096 + t] = (unsigned char)bi;
  }
}

// ------------------------- stable counting sort per (bh, round) ------------
__global__ __launch_bounds__(64) void sort_kernel(
    const unsigned char* __restrict__ buckets, int* __restrict__ st)
{
  __shared__ unsigned char sb[4096];
  __shared__ int cnts[64];
  int tid = threadIdx.x;
  const unsigned int* src4 = (const unsigned int*)(buckets + (size_t)blockIdx.x*4096);
  unsigned int* sb4 = (unsigned int*)sb;
  for (int i=tid; i<1024; i+=64) sb4[i] = src4[i];
  __syncthreads();
  unsigned int me = (unsigned int)tid;
  int cnt = 0;
  for (int t4=0; t4<1024; ++t4) {
    unsigned int w = sb4[t4];
    cnt += ((w & 255u) == me) + (((w>>8)&255u) == me)
         + (((w>>16)&255u) == me) + ((w>>24) == me);
  }
  cnts[tid] = cnt;
  __syncthreads();
  int base = 0;
  for (int j=0;j<tid;++j) base += cnts[j];
  int* dst = st + (size_t)blockIdx.x*4096;
  for (int t4=0; t4<1024; ++t4) {
    unsigned int w = sb4[t4];
#pragma unroll
    for (int q=0;q<4;++q)
      if (((w >> (8*q)) & 255u) == me) dst[base++] = t4*4 + q;
  }
}

// ------------------------- chunked attention, MFMA -------------------------
// block = (bh, chunk c); 64 queries x 128 keys (chunk c + chunk c-1).
// S = Q.K^T via split-bf16 MFMA (SQ planes); per-key 1/||k|| applied to the
// C-layout columns; softmax in registers (16-lane shuffle); P,V^T staged as
// 2-plane bf16; PV via 4-term MFMA.
template<int SQ>
__global__ __launch_bounds__(256) void attn_mfma(
    const float* __restrict__ qk, const float* __restrict__ v,
    const int* __restrict__ st, float* __restrict__ osc,
    float* __restrict__ logits)
{
  constexpr int RQ = 72;
  constexpr int RP = 136;
  constexpr int QKE = SQ*128*RQ;
  constexpr int PVE = 2*64*RP*2;
  constexpr int UE = (QKE > PVE ? QKE : PVE);
  __shared__ __align__(16) unsigned short uni[UE];
  __shared__ int sPos[128];
  __shared__ float sInv[128];
  unsigned short* sQK = uni;
  unsigned short* sP  = uni;
  unsigned short* sVT = uni + 2*64*RP;

  int tid = threadIdx.x;
  int bh = blockIdx.x >> 8;
  int c  = blockIdx.x & 255;
  int b = bh >> 3, hd = bh & 7;
  int r = c >> 6;
  int lane = tid & 63, wave = tid >> 6;
  int fr = lane & 15, fq = lane >> 4;
  int fk = fq * 8;

  if (tid < 128) {
    int cprev = (c + 255) & 255;
    int slot = (tid < 64) ? (c*64 + tid) : (cprev*64 + tid - 64);
    sPos[tid] = st[bh*16384 + slot];
  }
  __syncthreads();

  int row = tid >> 1, ks2 = (tid & 1) * 32;
  float vreg[32];
  {
    size_t rbase = ((size_t)(b*4096 + sPos[row]))*512 + hd*64 + ks2;
    const float* src  = qk + rbase;
    const float* vsrc = v  + rbase;
    float qreg[32];
    float ss = 0.f;
#pragma unroll
    for (int i=0;i<32;i+=4) {
      float4 x = *(const float4*)(src + i);
      qreg[i]=x.x; qreg[i+1]=x.y; qreg[i+2]=x.z; qreg[i+3]=x.w;
      ss += x.x*x.x + x.y*x.y + x.z*x.z + x.w*x.w;
      float4 y = *(const float4*)(vsrc + i);
      vreg[i]=y.x; vreg[i+1]=y.y; vreg[i+2]=y.z; vreg[i+3]=y.w;
    }
    ss += __shfl_xor(ss, 1, 64);
    if ((tid & 1) == 0) sInv[row] = 1.0f / fmaxf(sqrtf(ss), 1e-12f);
    unsigned short us[3][32];
#pragma unroll
    for (int i=0;i<32;++i) {
      float vv = qreg[i];
      unsigned short h0 = f2bf(vv);
      float r1 = vv - bf2f(h0);
      unsigned short h1 = f2bf(r1);
      us[0][i] = h0; us[1][i] = h1;
      if (SQ==3) { float r2 = r1 - bf2f(h1); us[2][i] = f2bf(r2); }
    }
#pragma unroll
    for (int p=0;p<SQ;++p) {
      uint4* d = (uint4*)&sQK[p*128*RQ + row*RQ + ks2];
      d[0] = *(const uint4*)&us[p][0];
      d[1] = *(const uint4*)&us[p][8];
      d[2] = *(const uint4*)&us[p][16];
      d[3] = *(const uint4*)&us[p][24];
    }
  }
  __syncthreads();

  floatx4 s[8];
#pragma unroll
  for (int nt=0;nt<8;++nt) s[nt] = (floatx4){0.f,0.f,0.f,0.f};
#pragma unroll
  for (int ks=0; ks<2; ++ks) {
    bf16x8 aQ[SQ];
#pragma unroll
    for (int p=0;p<SQ;++p)
      aQ[p] = *(const bf16x8*)&sQK[p*128*RQ + (wave*16 + fr)*RQ + ks*32 + fk];
#pragma unroll
    for (int nt=0;nt<8;++nt) {
      bf16x8 bK[SQ];
#pragma unroll
      for (int p=0;p<SQ;++p)
        bK[p] = *(const bf16x8*)&sQK[p*128*RQ + (nt*16 + fr)*RQ + ks*32 + fk];
      floatx4 cc = s[nt];
      if (SQ==3) {
        cc = __builtin_amdgcn_mfma_f32_16x16x32_bf16(aQ[2], bK[0], cc, 0,0,0);
        cc = __builtin_amdgcn_mfma_f32_16x16x32_bf16(aQ[1], bK[1], cc, 0,0,0);
        cc = __builtin_amdgcn_mfma_f32_16x16x32_bf16(aQ[0], bK[2], cc, 0,0,0);
      }
      cc = __builtin_amdgcn_mfma_f32_16x16x32_bf16(aQ[1], bK[0], cc, 0,0,0);
      cc = __builtin_amdgcn_mfma_f32_16x16x32_bf16(aQ[0], bK[1], cc, 0,0,0);
      cc = __builtin_amdgcn_mfma_f32_16x16x32_bf16(aQ[0], bK[0], cc, 0,0,0);
      s[nt] = cc;
    }
  }

  int ipos[4];
#pragma unroll
  for (int reg=0;reg<4;++reg) ipos[reg] = sPos[wave*16 + fq*4 + reg];
  float dv[8][4];
  float mx[4] = {-1e30f,-1e30f,-1e30f,-1e30f};
#pragma unroll
  for (int nt=0;nt<8;++nt) {
    float invj = sInv[nt*16 + fr];
    int jpos = sPos[nt*16 + fr];
#pragma unroll
    for (int reg=0;reg<4;++reg) {
      float d = s[nt][reg] * invj * 0.125f;
      if (jpos == ipos[reg]) d = -5.0e4f;
      dv[nt][reg] = d;
      mx[reg] = fmaxf(mx[reg], d);
    }
  }
#pragma unroll
  for (int reg=0;reg<4;++reg) {
    mx[reg] = fmaxf(mx[reg], __shfl_xor(mx[reg], 1, 64));
    mx[reg] = fmaxf(mx[reg], __shfl_xor(mx[reg], 2, 64));
    mx[reg] = fmaxf(mx[reg], __shfl_xor(mx[reg], 4, 64));
    mx[reg] = fmaxf(mx[reg], __shfl_xor(mx[reg], 8, 64));
  }
  float sum[4] = {0.f,0.f,0.f,0.f};
#pragma unroll
  for (int nt=0;nt<8;++nt)
#pragma unroll
    for (int reg=0;reg<4;++reg) sum[reg] += expf(dv[nt][reg] - mx[reg]);
  float lse[4];
#pragma unroll
  for (int reg=0;reg<4;++reg) {
    sum[reg] += __shfl_xor(sum[reg], 1, 64);
    sum[reg] += __shfl_xor(sum[reg], 2, 64);
    sum[reg] += __shfl_xor(sum[reg], 4, 64);
    sum[reg] += __shfl_xor(sum[reg], 8, 64);
    lse[reg] = mx[reg] + logf(sum[reg]);
  }
  if (fr == 0) {
#pragma unroll
    for (int reg=0;reg<4;++reg)
      logits[((size_t)(bh*4 + r))*4096 + ipos[reg]] = lse[reg];
  }
#pragma unroll
  for (int nt=0;nt<8;++nt)
#pragma unroll
    for (int reg=0;reg<4;++reg) dv[nt][reg] = expf(dv[nt][reg] - lse[reg]);

  __syncthreads();

#pragma unroll
  for (int nt=0;nt<8;++nt) {
    int key = nt*16 + fr;
#pragma unroll
    for (int reg=0;reg<4;++reg) {
      int m = wave*16 + fq*4 + reg;
      float p = dv[nt][reg];
      unsigned short h0 = f2bf(p);
      sP[0*64*RP + m*RP + key] = h0;
      sP[1*64*RP + m*RP + key] = f2bf(p - bf2f(h0));
    }
  }
#pragma unroll
  for (int i=0;i<32;++i) {
    int dh = ks2 + i;
    float vv = vreg[i];
    unsigned short h0 = f2bf(vv);
    sVT[0*64*RP + dh*RP + row] = h0;
    sVT[1*64*RP + dh*RP + row] = f2bf(vv - bf2f(h0));
  }
  __syncthreads();

  size_t obase = ((size_t)(bh*4 + r)) * 4096;
#pragma unroll
  for (int dt=0;dt<4;++dt) {
    floatx4 o = (floatx4){0.f,0.f,0.f,0.f};
#pragma unroll
    for (int ks=0; ks<4; ++ks) {
      bf16x8 aP0 = *(const bf16x8*)&sP[0*64*RP + (wave*16 + fr)*RP + ks*32 + fk];
      bf16x8 aP1 = *(const bf16x8*)&sP[1*64*RP + (wave*16 + fr)*RP + ks*32 + fk];
      bf16x8 bV0 = *(const bf16x8*)&sVT[0*64*RP + (dt*16 + fr)*RP + ks*32 + fk];
      bf16x8 bV1 = *(const bf16x8*)&sVT[1*64*RP + (dt*16 + fr)*RP + ks*32 + fk];
      o = __builtin_amdgcn_mfma_f32_16x16x32_bf16(aP1, bV1, o, 0,0,0);
      o = __builtin_amdgcn_mfma_f32_16x16x32_bf16(aP1, bV0, o, 0,0,0);
      o = __builtin_amdgcn_mfma_f32_16x16x32_bf16(aP0, bV1, o, 0,0,0);
      o = __builtin_amdgcn_mfma_f32_16x16x32_bf16(aP0, bV0, o, 0,0,0);
    }
    int dh = dt*16 + fr;
#pragma unroll
    for (int reg=0;reg<4;++reg) {
      int m = wave*16 + fq*4 + reg;
      osc[(obase + sPos[m])*64 + dh] = o[reg];
    }
  }
}

// ------------------------- combine rounds + merge heads --------------------
__global__ __launch_bounds__(256) void combine_kernel(
    const float* __restrict__ osc, const float* __restrict__ logits,
    float* __restrict__ merged)
{
  int idx = blockIdx.x;
  int b = idx >> 12, t = idx & 4095;
  int tid = threadIdx.x;
  __shared__ float w[8][4];
  if (tid < 8) {
    size_t lbase = ((size_t)(b*8 + tid)) * 4 * 4096 + t;
    float l0 = logits[lbase], l1 = logits[lbase + 4096],
          l2 = logits[lbase + 8192], l3 = logits[lbase + 12288];
    float m = fmaxf(fmaxf(l0,l1), fmaxf(l2,l3));
    float e0 = expf(l0-m), e1 = expf(l1-m), e2 = expf(l2-m), e3 = expf(l3-m);
    float inv = 1.0f/(e0+e1+e2+e3);
    w[tid][0]=e0*inv; w[tid][1]=e1*inv; w[tid][2]=e2*inv; w[tid][3]=e3*inv;
  }
  __syncthreads();
#pragma unroll
  for (int rep=0; rep<2; ++rep) {
    int d = tid + rep*256;
    int hd = d >> 6, dh = d & 63;
    size_t obase = (((size_t)(b*8 + hd)) * 4 * 4096 + t) * 64 + dh;
    float o = w[hd][0]*osc[obase]
            + w[hd][1]*osc[obase + 262144]
            + w[hd][2]*osc[obase + 524288]
            + w[hd][3]*osc[obase + 786432];
    merged[(size_t)idx*512 + d] = o;
  }
}

// ------------------------- residual + LayerNorm (in-place on h) ------------
__global__ __launch_bounds__(256) void ln_residual_kernel(
    float* __restrict__ h, const float* __restrict__ a,
    const float* __restrict__ g, const float* __restrict__ bb)
{
  int row = blockIdx.x;
  int tid = threadIdx.x;
  size_t base = (size_t)row * 512;
  float x0 = h[base + tid]       + a[base + tid];
  float x1 = h[base + tid + 256] + a[base + tid + 256];
  float s  = x0 + x1;
  float sq = x0*x0 + x1*x1;
#pragma unroll
  for (int off = 32; off > 0; off >>= 1) {
    s  += __shfl_down(s, off, 64);
    sq += __shfl_down(sq, off, 64);
  }
  __shared__ float rs[4], rq[4], sm[2];
  int wv = tid >> 6;
  if ((tid & 63) == 0) { rs[wv] = s; rq[wv] = sq; }
  __syncthreads();
  if (tid == 0) {
    float S = rs[0]+rs[1]+rs[2]+rs[3];
    float Q = rq[0]+rq[1]+rq[2]+rq[3];
    float m = S * (1.0f/512.0f);
    float var = Q * (1.0f/512.0f) - m*m;
    sm[0] = m; sm[1] = rsqrtf(var + 1e-5f);
  }
  __syncthreads();
  float m = sm[0], rstd = sm[1];
  h[base + tid]       = (x0 - m) * rstd * g[tid]       + bb[tid];
  h[base + tid + 256] = (x1 - m) * rstd * g[tid + 256] + bb[tid + 256];
}

// ------------------------- final LN + projection ---------------------------
__global__ __launch_bounds__(256) void final_kernel(
    const float* __restrict__ h, const float* __restrict__ g, const float* __restrict__ bb,
    const float* __restrict__ Wp, const float* __restrict__ bp, float* __restrict__ out)
{
  int idx = blockIdx.x;
  int b = idx >> 9, tp = idx & 511;
  size_t base = ((size_t)(b*4096 + 3584 + tp)) * 512;
  int tid = threadIdx.x;
  float x0 = h[base + tid], x1 = h[base + tid + 256];
  float s = x0 + x1, sq = x0*x0 + x1*x1;
#pragma unroll
  for (int off = 32; off > 0; off >>= 1) {
    s  += __shfl_down(s, off, 64);
    sq += __shfl_down(sq, off, 64);
  }
  __shared__ float rs[4], rq[4], sm[2];
  int wv = tid >> 6;
  if ((tid & 63) == 0) { rs[wv] = s; rq[wv] = sq; }
  __syncthreads();
  if (tid == 0) {
    float S = rs[0]+rs[1]+rs[2]+rs[3];
    float Q = rq[0]+rq[1]+rq[2]+rq[3];
    float m = S*(1.f/512.f);
    float var = Q*(1.f/512.f) - m*m;
    sm[0]=m; sm[1]=rsqrtf(var+1e-5f);
  }
  __syncthreads();
  __shared__ float xn[512];
  float m = sm[0], rstd = sm[1];
  xn[tid]     = (x0-m)*rstd*g[tid]     + bb[tid];
  xn[tid+256] = (x1-m)*rstd*g[tid+256] + bb[tid+256];
  __syncthreads();
  if (tid < 224) {
    int col = tid >> 5, lane = tid & 31;
    float p = 0.f;
    for (int f = lane; f < 512; f += 32) p += xn[f]*Wp[f*7 + col];
#pragma unroll
    for (int off=16; off>0; off>>=1) p += __shfl_down(p, off, 32);
    if (lane == 0) out[(size_t)idx*7 + col] = p + bp[col];
  }
}

// ---------------------------------------------------------------------------
extern "C" void kernel_launch(void* const* d_in, const int* in_sizes, int n_in,
                              void* d_out, int out_size, void* d_ws, size_t ws_size,
                              hipStream_t stream)
{
  (void)in_sizes; (void)n_in; (void)out_size; (void)ws_size;
  const float* x_enc  = (const float*)d_in[0];
  const float* x_dec  = (const float*)d_in[1];
  const int*   xm_enc = (const int*)d_in[2];
  const int*   xm_dec = (const int*)d_in[3];
  const float* conv_w = (const float*)d_in[4];
  const float* month  = (const float*)d_in[5];
  const float* day    = (const float*)d_in[6];
  const float* wday   = (const float*)d_in[7];
  const float* hourE  = (const float*)d_in[8];
  const float* minE   = (const float*)d_in[9];
  const float* W_qk   = (const float*)d_in[10];
  const float* W_v    = (const float*)d_in[11];
  const float* W_out  = (const float*)d_in[12];
  const float* b_out  = (const float*)d_in[13];
  const float* rots   = (const float*)d_in[14];
  const float* ln1_g  = (const float*)d_in[15];
  const float* ln1_b  = (const float*)d_in[16];
  const float* W_ff1  = (const float*)d_in[17];
  const float* b_ff1  = (const float*)d_in[18];
  const float* W_ff2  = (const float*)d_in[19];
  const float* b_ff2  = (const float*)d_in[20];
  const float* ln2_g  = (const float*)d_in[21];
  const float* ln2_b  = (const float*)d_in[22];
  const float* lnf_g  = (const float*)d_in[23];
  const float* lnf_b  = (const float*)d_in[24];
  const float* W_proj = (const float*)d_in[25];
  const float* b_proj = (const float*)d_in[26];

  float* h    = (float*)d_ws;            // 8M floats
  float* bufA = h    + 8388608ull;       // 8M
  float* bufB = bufA + 8388608ull;       // 8M
  float* osc  = bufB + 8388608ull;       // 32M (attn out / FFN mid / pe / Wt)
  float* lg   = osc  + 33554432ull;      // 512K
  int*   stp  = (int*)(lg + 524288ull);  // 512K ints
  unsigned char* bkt = (unsigned char*)(stp + 524288ull); // 512KB
  float* pe   = osc;                     // only live during embed
  unsigned short* WtA = (unsigned short*)osc;   // Wt for v/out (osc dead then)
  unsigned short* WtB = (unsigned short*)bufB;  // Wt for ff1/ff2 (bufB dead then)

  pe_kernel<<<4096, 256, 0, stream>>>(pe);
  embed_kernel<<<16384, 256, 0, stream>>>(x_enc, x_dec, xm_enc, xm_dec, conv_w,
                                          month, day, wday, hourE, minE, pe, h);
  for (int l = 0; l < 2; ++l) {
    const float* Wqk = W_qk + (size_t)l*262144;
    const float* Wv  = W_v  + (size_t)l*262144;
    const float* Wo  = W_out+ (size_t)l*262144;
    const float* Wf1 = W_ff1 + (size_t)l*1048576;
    const float* Wf2 = W_ff2 + (size_t)l*1048576;
    const float* rot = rots + (size_t)l*8192;

    // qk projection: precise (feeds LSH argmax directly)
    gemm_kernel<0><<<dim3(128,4), 256, 0, stream>>>(h, Wqk, nullptr, bufA, 16384, 512, 512);
    // v projection: split-bf16 MFMA (x3 on layer 0, x2 on layer 1)
    if (l == 0) {
      wsplit_kernel<3><<<dim3(16,16), 256, 0, stream>>>(Wv, WtA, 512, 512);
      gemm_mfma<3,0><<<dim3(128,4), 256, 0, stream>>>(h, WtA, nullptr, bufB, 16384, 512, 512);
    } else {
      wsplit_kernel<2><<<dim3(16,16), 256, 0, stream>>>(Wv, WtA, 512, 512);
      gemm_mfma<2,0><<<dim3(128,4), 256, 0, stream>>>(h, WtA, nullptr, bufB, 16384, 512, 512);
    }
    hash_kernel<<<65536, 256, 0, stream>>>(bufA, rot, bkt);
    sort_kernel<<<128, 64, 0, stream>>>(bkt, stp);
    if (l == 0)
      attn_mfma<3><<<8192, 256, 0, stream>>>(bufA, bufB, stp, osc, lg);
    else
      attn_mfma<2><<<8192, 256, 0, stream>>>(bufA, bufB, stp, osc, lg);
    combine_kernel<<<16384, 256, 0, stream>>>(osc, lg, bufA);
    // out projection
    if (l == 0) {
      wsplit_kernel<3><<<dim3(16,16), 256, 0, stream>>>(Wo, WtA, 512, 512);
      gemm_mfma<3,0><<<dim3(128,4), 256, 0, stream>>>(bufA, WtA, b_out + l*512, bufB, 16384, 512, 512);
    } else {
      wsplit_kernel<2><<<dim3(16,16), 256, 0, stream>>>(Wo, WtA, 512, 512);
      gemm_mfma<2,0><<<dim3(128,4), 256, 0, stream>>>(bufA, WtA, b_out + l*512, bufB, 16384, 512, 512);
    }
    ln_residual_kernel<<<16384, 256, 0, stream>>>(h, bufB, ln1_g + l*512, ln1_b + l*512);
    // FFN
    if (l == 0) {
      wsplit_kernel<3><<<dim3(16,64), 256, 0, stream>>>(Wf1, WtB, 512, 2048);
      gemm_mfma<3,1><<<dim3(128,16), 256, 0, stream>>>(h, WtB, b_ff1 + l*2048, osc, 16384, 2048, 512);
      wsplit_kernel<3><<<dim3(64,16), 256, 0, stream>>>(Wf2, WtB, 2048, 512);
      gemm_mfma<3,0><<<dim3(128,4), 256, 0, stream>>>(osc, WtB, b_ff2 + l*512, bufA, 16384, 512, 2048);
    } else {
      wsplit_kernel<2><<<dim3(16,64), 256, 0, stream>>>(Wf1, WtB, 512, 2048);
      gemm_mfma<2,1><<<dim3(128,16), 256, 0, stream>>>(h, WtB, b_ff1 + l*2048, osc, 16384, 2048, 512);
      wsplit_kernel<2><<<dim3(64,16), 256, 0, stream>>>(Wf2, WtB, 2048, 512);
      gemm_mfma<2,0><<<dim3(128,4), 256, 0, stream>>>(osc, WtB, b_ff2 + l*512, bufA, 16384, 512, 2048);
    }
    ln_residual_kernel<<<16384, 256, 0, stream>>>(h, bufA, ln2_g + l*512, ln2_b + l*512);
  }
  final_kernel<<<2048, 256, 0, stream>>>(h, lnf_g, lnf_b, W_proj, b_proj, (float*)d_out);
}